// Round 12
// baseline (524.916 us; speedup 1.0000x reference)
//
#include <hip/hip_runtime.h>
#include <math.h>

#define DEV __device__ __forceinline__

typedef __attribute__((ext_vector_type(4))) float f32x4;
typedef __attribute__((ext_vector_type(4))) unsigned short u16x4;
typedef __attribute__((ext_vector_type(8))) unsigned short u16x8;
typedef __attribute__((ext_vector_type(8))) __bf16 bfv8;

DEV unsigned short f2bf(float f) {
  unsigned u = __builtin_bit_cast(unsigned, f);
  u = (u + 0x7FFFu + ((u >> 16) & 1u)) >> 16;
  return (unsigned short)u;
}
DEV float bf2f(unsigned short h) {
  unsigned u = ((unsigned)h) << 16;
  return __builtin_bit_cast(float, u);
}

DEV f32x4 mfma16(u16x8 a, u16x8 b, f32x4 c) {
  return __builtin_amdgcn_mfma_f32_16x16x32_bf16(
      __builtin_bit_cast(bfv8, a), __builtin_bit_cast(bfv8, b), c, 0, 0, 0);
}

DEV void gload_lds16(const unsigned short* g, unsigned short* s) {
  __builtin_amdgcn_global_load_lds(
      (const __attribute__((address_space(1))) void*)g,
      (__attribute__((address_space(3))) void*)s, 16, 0, 0);
}

template <int N>
DEV void vmcnt_wait() {
  if constexpr (N == 0) asm volatile("s_waitcnt vmcnt(0)" ::: "memory");
  else if constexpr (N == 4) asm volatile("s_waitcnt vmcnt(4)" ::: "memory");
  else if constexpr (N == 8) asm volatile("s_waitcnt vmcnt(8)" ::: "memory");
}

// ---------------------------------------------------------------------------
// 8-phase 256x256 bf16 GEMM, deep-staggered (m201-faithful), in_proj.
// K=2048, BK=64, 512 thr / 8 waves (2M x 4N), 2-slot LDS ring (128 KB).
// 4 phases/K-tile (one 32-row C-quadrant each, 16 MFMA); B-frags register-
// resident per tile (read once at P0). Stagger: tile t stages
// {P0:Ah0(t+1), P1:Ah1(t+1), P2:Bh0(t+2), P3:Bh1(t+2)+vmcnt(4)} --
// A leads 4 phases, B leads 6; one counted vmcnt per K-tile, never 0
// in steady state. XOR chunk swizzle (verified 0 conflicts).
// ---------------------------------------------------------------------------
__global__ __launch_bounds__(512, 2) void gemm8_in(
    const unsigned short* __restrict__ A, const unsigned short* __restrict__ Bt,
    unsigned short* __restrict__ o_z, unsigned short* __restrict__ o_xbc,
    float* __restrict__ o_dt) {
  constexpr int K = 2048, NT = K / 64;
  __shared__ __align__(16) unsigned short As[2][256 * 64];
  __shared__ __align__(16) unsigned short Bs[2][256 * 64];
  const int tid = threadIdx.x;
  const int lane = tid & 63, w = tid >> 6;
  const int l16 = lane & 15, lq = lane >> 4;
  const int wr = w >> 2, wc = w & 3;  // 2M x 4N
  const int nwg = gridDim.x * gridDim.y;
  int lin = blockIdx.y * gridDim.x + blockIdx.x;
  lin = (lin & 7) * (nwg >> 3) + (lin >> 3);
  const int m0 = (lin / gridDim.x) * 256, n0 = (lin % gridDim.x) * 256;
  const int srow = lane >> 3;
  const int schk = (lane & 7) ^ srow;
  const unsigned short* Ag = A + (size_t)(m0 + srow) * K + schk * 8;
  const unsigned short* Bg = Bt + (size_t)(n0 + srow) * K + schk * 8;
  const int px0 = lq ^ (l16 & 7);
  const int px1 = (4 + lq) ^ (l16 & 7);

  f32x4 acc[8][4] = {};  // [quad*2+mf][nf]

  auto stA = [&](int sl, int h, int kt) {
#pragma unroll
    for (int i = 0; i < 2; ++i) {
      const int rb = h * 128 + i * 64 + w * 8;
      gload_lds16(Ag + (size_t)rb * K + kt * 64, &As[sl][rb * 64]);
    }
  };
  auto stB = [&](int sl, int h, int kt) {
#pragma unroll
    for (int i = 0; i < 2; ++i) {
      const int rb = h * 128 + i * 64 + w * 8;
      gload_lds16(Bg + (size_t)rb * K + kt * 64, &Bs[sl][rb * 64]);
    }
  };
  auto rdA = [&](int sl, int row, int k2) -> u16x8 {
    return *(const u16x8*)(&As[sl][row * 64 + (k2 ? px1 : px0) * 8]);
  };
  auto rdB = [&](int sl, int row, int k2) -> u16x8 {
    return *(const u16x8*)(&Bs[sl][row * 64 + (k2 ? px1 : px0) * 8]);
  };

  // prologue: A(0) full, B(0) full, B(1) full; allow B(1) outstanding
  stA(0, 0, 0); stA(0, 1, 0);
  stB(0, 0, 0); stB(0, 1, 0);
  stB(1, 0, 1); stB(1, 1, 1);
  vmcnt_wait<4>();
  __builtin_amdgcn_s_barrier();

  u16x8 br[4][2];
  for (int t = 0; t < NT; ++t) {
    const int sl = t & 1, so = sl ^ 1;
    const bool hasA = (t + 1 < NT), hasB = (t + 2 < NT);
#pragma unroll
    for (int p = 0; p < 4; ++p) {
      // ---- read section (data guaranteed by previous phase boundary)
      u16x8 ar[2][2];
#pragma unroll
      for (int mf = 0; mf < 2; ++mf) {
        const int row = wr * 128 + p * 32 + mf * 16 + l16;
        ar[mf][0] = rdA(sl, row, 0);
        ar[mf][1] = rdA(sl, row, 1);
      }
      if (p == 0) {
#pragma unroll
        for (int nf = 0; nf < 4; ++nf) {
          const int row = wc * 64 + nf * 16 + l16;
          br[nf][0] = rdB(sl, row, 0);
          br[nf][1] = rdB(sl, row, 1);
        }
      }
      // ---- stage section
      if (p == 0) { if (hasA) stA(so, 0, t + 1); }
      else if (p == 1) { if (hasA) stA(so, 1, t + 1); }
      else if (p == 2) { if (hasB) stB(sl, 0, t + 2); }
      else {
        if (hasB) stB(sl, 1, t + 2);
        if (t < NT - 2) vmcnt_wait<4>();
        else vmcnt_wait<0>();
      }
      __builtin_amdgcn_s_barrier();
      __builtin_amdgcn_s_setprio(1);
#pragma unroll
      for (int nf = 0; nf < 4; ++nf)
#pragma unroll
        for (int mf = 0; mf < 2; ++mf) {
          acc[p * 2 + mf][nf] = mfma16(ar[mf][0], br[nf][0], acc[p * 2 + mf][nf]);
          acc[p * 2 + mf][nf] = mfma16(ar[mf][1], br[nf][1], acc[p * 2 + mf][nf]);
        }
      __builtin_amdgcn_s_setprio(0);
      __builtin_amdgcn_s_barrier();
    }
  }

#pragma unroll
  for (int q = 0; q < 8; ++q) {
#pragma unroll
    for (int nf = 0; nf < 4; ++nf) {
      const int col = n0 + wc * 64 + nf * 16 + l16;
#pragma unroll
      for (int r = 0; r < 4; ++r) {
        const int row = m0 + wr * 128 + (q >> 1) * 32 + (q & 1) * 16 + lq * 4 + r;
        float v = acc[q][nf][r];
        if (col < 4096) o_z[(size_t)row * 4096 + col] = f2bf(v);
        else if (col < 8448) o_xbc[(size_t)row * 4352 + (col - 4096)] = f2bf(v);
        else if (col < 8512) o_dt[(size_t)row * 64 + (col - 8448)] = v;
      }
    }
  }
}

// ---------------------------------------------------------------------------
// Pipelined bf16 GEMM (R7/R8 structure) for out_proj: 128x128, 4 waves,
// BK=32, 3-buffer ring, counted vmcnt(4). += resid -> f32 (N=2048).
// ---------------------------------------------------------------------------
__global__ __launch_bounds__(256, 3) void gemm_p(
    const unsigned short* __restrict__ A, const unsigned short* __restrict__ Bt,
    int K, float* __restrict__ o_c, const float* __restrict__ resid) {
  __shared__ __align__(16) unsigned short As[3][128 * 32];
  __shared__ __align__(16) unsigned short Bs[3][128 * 32];
  const int tid = threadIdx.x;
  const int lane = tid & 63, w = tid >> 6;
  const int l16 = lane & 15, lq = lane >> 4;
  const int wr = w >> 1, wc = w & 1;
  const int nwg = gridDim.x * gridDim.y;
  int lin = blockIdx.y * gridDim.x + blockIdx.x;
  lin = (lin & 7) * (nwg >> 3) + (lin >> 3);
  const int m0 = (lin / gridDim.x) * 128, n0 = (lin % gridDim.x) * 128;
  const int lrow = lane >> 2;
  const int gq = (lane & 3) ^ ((lrow >> 1) & 3);
  const int cq = lq ^ ((l16 >> 1) & 3);

  const unsigned short* Ag = A + (size_t)(m0 + lrow) * K + gq * 8;
  const unsigned short* Bg = Bt + (size_t)(n0 + lrow) * K + gq * 8;

  f32x4 acc[4][4] = {};

  auto stage = [&](int bi, int kt) {
#pragma unroll
    for (int i = 0; i < 2; ++i) {
      const int rb = (w + i * 4) * 16;
      gload_lds16(Ag + (size_t)rb * K + kt * 32, &As[bi][rb * 32]);
    }
#pragma unroll
    for (int i = 0; i < 2; ++i) {
      const int rb = (w + i * 4) * 16;
      gload_lds16(Bg + (size_t)rb * K + kt * 32, &Bs[bi][rb * 32]);
    }
  };

  const int nt = K / 32;
  stage(0, 0);
  stage(1, 1);

  for (int k = 0; k < nt; ++k) {
    const int cb = k % 3;
    if (k < nt - 1) vmcnt_wait<4>();
    else vmcnt_wait<0>();
    __builtin_amdgcn_s_barrier();
    if (k + 2 < nt) stage((k + 2) % 3, k + 2);

    u16x8 af[4], bf[4];
#pragma unroll
    for (int mf = 0; mf < 4; ++mf)
      af[mf] = *(const u16x8*)(&As[cb][(wr * 64 + mf * 16 + l16) * 32 + cq * 8]);
#pragma unroll
    for (int nf = 0; nf < 4; ++nf)
      bf[nf] = *(const u16x8*)(&Bs[cb][(wc * 64 + nf * 16 + l16) * 32 + cq * 8]);

    __builtin_amdgcn_s_setprio(1);
#pragma unroll
    for (int mf = 0; mf < 4; ++mf)
#pragma unroll
      for (int nf = 0; nf < 4; ++nf)
        acc[mf][nf] = mfma16(af[mf], bf[nf], acc[mf][nf]);
    __builtin_amdgcn_s_setprio(0);
  }

#pragma unroll
  for (int mf = 0; mf < 4; ++mf) {
#pragma unroll
    for (int nf = 0; nf < 4; ++nf) {
      const int col = n0 + wc * 64 + nf * 16 + l16;
#pragma unroll
      for (int r = 0; r < 4; ++r) {
        const int row = m0 + wr * 64 + mf * 16 + lq * 4 + r;
        size_t idx = (size_t)row * 2048 + col;
        o_c[idx] = acc[mf][nf][r] + resid[idx];
      }
    }
  }
}

// ---------------------------------------------------------------------------
// x f32 -> bf16 (elementwise, 8/thread)
// ---------------------------------------------------------------------------
__global__ __launch_bounds__(256) void convert_bf16(
    const float* __restrict__ in, unsigned short* __restrict__ out) {
  const size_t i = ((size_t)blockIdx.x * 256 + threadIdx.x) * 8;
  f32x4 a = *(const f32x4*)(in + i);
  f32x4 b = *(const f32x4*)(in + i + 4);
  u16x8 o;
#pragma unroll
  for (int j = 0; j < 4; ++j) { o[j] = f2bf(a[j]); o[j + 4] = f2bf(b[j]); }
  *(u16x8*)(out + i) = o;
}

// ---------------------------------------------------------------------------
// transpose+convert: in[R][C] f32 -> out[Cpad][R] bf16 (rows c>=C zero-filled)
// ---------------------------------------------------------------------------
__global__ __launch_bounds__(256) void transpose_conv(
    const float* __restrict__ in, unsigned short* __restrict__ out, int R,
    int C) {
  __shared__ __align__(16) unsigned short T[64][72];
  const int c0 = blockIdx.x * 64, r0 = blockIdx.y * 64;
  const int tid = threadIdx.x;
#pragma unroll
  for (int it = 0; it < 4; ++it) {
    int r = it * 16 + (tid >> 4);
    int c = (tid & 15) * 4;
    f32x4 v = {0.f, 0.f, 0.f, 0.f};
    if (c0 + c < C) v = *(const f32x4*)(in + (size_t)(r0 + r) * C + c0 + c);
#pragma unroll
    for (int j = 0; j < 4; ++j) T[c + j][r] = f2bf(v[j]);
  }
  __syncthreads();
  const int nr = tid >> 2, kc = (tid & 3) * 16;
  u16x8 a = *(const u16x8*)(&T[nr][kc]);
  u16x8 b = *(const u16x8*)(&T[nr][kc + 8]);
  unsigned short* o = out + (size_t)(c0 + nr) * R + r0 + kc;
  *(u16x8*)o = a;
  *(u16x8*)(o + 8) = b;
}

// ---------------------------------------------------------------------------
// Depthwise causal conv (4 taps) + bias + SiLU, bf16 in/out, L-tiled x4
// ---------------------------------------------------------------------------
__global__ __launch_bounds__(256) void conv_kernel(
    const unsigned short* __restrict__ raw, const float* __restrict__ cw,
    const float* __restrict__ cb, unsigned short* __restrict__ xbc) {
  const int ch4 = blockIdx.x * 256 + threadIdx.x;
  if (ch4 >= 1088) return;
  const int ch = ch4 * 4;
  const int r0 = blockIdx.y * 4;
  const int l0 = r0 & 2047;
  f32x4 w0 = *(const f32x4*)(cw + ch * 4);
  f32x4 w1 = *(const f32x4*)(cw + ch * 4 + 4);
  f32x4 w2 = *(const f32x4*)(cw + ch * 4 + 8);
  f32x4 w3 = *(const f32x4*)(cw + ch * 4 + 12);
  f32x4 bias = *(const f32x4*)(cb + ch);
  f32x4 v[7];
#pragma unroll
  for (int i = 0; i < 7; ++i) {
    if (l0 - 3 + i >= 0) {
      u16x4 h = *(const u16x4*)(raw + (size_t)(r0 - 3 + i) * 4352 + ch);
      v[i] = (f32x4){bf2f(h[0]), bf2f(h[1]), bf2f(h[2]), bf2f(h[3])};
    } else {
      v[i] = (f32x4){0.f, 0.f, 0.f, 0.f};
    }
  }
#pragma unroll
  for (int j = 0; j < 4; ++j) {
    f32x4 acc = bias;
#pragma unroll
    for (int k = 0; k < 4; ++k) {
      acc[0] += w0[k] * v[j + k][0];
      acc[1] += w1[k] * v[j + k][1];
      acc[2] += w2[k] * v[j + k][2];
      acc[3] += w3[k] * v[j + k][3];
    }
    u16x4 o;
#pragma unroll
    for (int q = 0; q < 4; ++q) {
      float s = acc[q] / (1.0f + __expf(-acc[q]));
      o[q] = f2bf(s);
    }
    *(u16x4*)(xbc + (size_t)(r0 + j) * 4352 + ch) = o;
  }
}

// ---------------------------------------------------------------------------
// dt softplus (in place) + per-chunk cumsum, wave shuffle scan (1 barrier)
// ---------------------------------------------------------------------------
__global__ __launch_bounds__(256) void dt_kernel(
    float* __restrict__ dtb, const float* __restrict__ dt_bias,
    const float* __restrict__ A_log, float* __restrict__ Acs) {
  __shared__ float ws[4];
  const int blk = blockIdx.x;
  const int c = blk & 7, h = (blk >> 3) & 63, b = blk >> 9;
  const int t = threadIdx.x;
  const int lane = t & 63, w = t >> 6;
  const int row = b * 2048 + c * 256 + t;
  float xv = dtb[(size_t)row * 64 + h] + dt_bias[h];
  float dt = (xv > 20.0f) ? xv : log1pf(__expf(xv));
  dtb[(size_t)row * 64 + h] = dt;
  float s = dt * (-__expf(A_log[h]));
#pragma unroll
  for (int off = 1; off < 64; off <<= 1) {
    float v = __shfl_up(s, off, 64);
    if (lane >= off) s += v;
  }
  if (lane == 63) ws[w] = s;
  __syncthreads();
  float base = 0.0f;
#pragma unroll
  for (int i = 0; i < 4; ++i)
    if (i < w) base += ws[i];
  Acs[((size_t)((b * 64 + h) * 8 + c)) * 256 + t] = s + base;
}

// ---------------------------------------------------------------------------
// G[bc][i][j] = sum_n Cm[i][n]*Bm[j][n] (head-independent)
// ---------------------------------------------------------------------------
__global__ __launch_bounds__(256) void g_kernel(
    const unsigned short* __restrict__ xbc, float* __restrict__ G) {
  const int bc = blockIdx.y;
  const int i0 = (blockIdx.x >> 2) * 64, j0 = (blockIdx.x & 3) * 64;
  const int tid = threadIdx.x;
  const int lane = tid & 63, w = tid >> 6;
  const int l16 = lane & 15, lq = lane >> 4;
  const unsigned short* base = xbc + (size_t)bc * 256 * 4352;
  f32x4 acc[4] = {};
#pragma unroll
  for (int ks = 0; ks < 4; ++ks) {
    int nb = ks * 32 + lq * 8;
    u16x8 af = *(const u16x8*)(base + (size_t)(i0 + w * 16 + l16) * 4352 + 4224 + nb);
#pragma unroll
    for (int jf = 0; jf < 4; ++jf) {
      u16x8 bb = *(const u16x8*)(base + (size_t)(j0 + jf * 16 + l16) * 4352 + 4096 + nb);
      acc[jf] = mfma16(af, bb, acc[jf]);
    }
  }
  float* Gt = G + (size_t)bc * 65536;
#pragma unroll
  for (int jf = 0; jf < 4; ++jf)
#pragma unroll
    for (int r = 0; r < 4; ++r)
      Gt[(i0 + w * 16 + lq * 4 + r) * 256 + j0 + jf * 16 + l16] = acc[jf][r];
}

// ---------------------------------------------------------------------------
// Per-chunk states: states[p][n] (bf16) = sum_t Bm[t][n]*decay(t)*X[t][p]
// ---------------------------------------------------------------------------
__global__ __launch_bounds__(512) void ssd_states(
    const unsigned short* __restrict__ xbc, const float* __restrict__ dtb,
    const float* __restrict__ Acs, unsigned short* __restrict__ statesb) {
  __shared__ __align__(16) unsigned short Xt[64 * 264];
  __shared__ __align__(16) unsigned short BmT[128 * 72];
  __shared__ float As_s[256];
  const int h = blockIdx.x, c = blockIdx.y, b = blockIdx.z;
  const int tid = threadIdx.x;
  const int lane = tid & 63, w = tid >> 6;
  const int l16 = lane & 15, lq = lane >> 4;
  const int row0 = b * 2048 + c * 256;

  if (tid < 256) As_s[tid] = Acs[((size_t)((b * 64 + h) * 8 + c)) * 256 + tid];
#pragma unroll
  for (int it = 0; it < 2; ++it) {
    int pb = tid & 15;
    int tb = it * 32 + (tid >> 4);
    float rr[4][4];
#pragma unroll
    for (int i = 0; i < 4; ++i) {
      int row = row0 + tb * 4 + i;
      u16x4 v = *(const u16x4*)(xbc + (size_t)row * 4352 + h * 64 + pb * 4);
      float dtv = dtb[(size_t)row * 64 + h];
#pragma unroll
      for (int j = 0; j < 4; ++j) rr[i][j] = bf2f(v[j]) * dtv;
    }
#pragma unroll
    for (int j = 0; j < 4; ++j) {
      u16x4 hh = {f2bf(rr[0][j]), f2bf(rr[1][j]), f2bf(rr[2][j]), f2bf(rr[3][j])};
      *(u16x4*)(&Xt[(pb * 4 + j) * 264 + tb * 4]) = hh;
    }
  }
  __syncthreads();

  f32x4 accS[4] = {};
  const float Alast = As_s[255];
  for (int part = 0; part < 4; ++part) {
    if (part) __syncthreads();
    {
      int nb = tid & 31;
      int tb = tid >> 5;
      float rr[4][4];
#pragma unroll
      for (int i = 0; i < 4; ++i) {
        int t = part * 64 + tb * 4 + i;
        int row = row0 + t;
        float dec = __expf(Alast - As_s[t]);
        u16x4 v = *(const u16x4*)(xbc + (size_t)row * 4352 + 4096 + nb * 4);
#pragma unroll
        for (int j = 0; j < 4; ++j) rr[i][j] = bf2f(v[j]) * dec;
      }
#pragma unroll
      for (int j = 0; j < 4; ++j) {
        u16x4 hh = {f2bf(rr[0][j]), f2bf(rr[1][j]), f2bf(rr[2][j]), f2bf(rr[3][j])};
        *(u16x4*)(&BmT[(nb * 4 + j) * 72 + tb * 4]) = hh;
      }
    }
    __syncthreads();
#pragma unroll
    for (int ks = 0; ks < 2; ++ks) {
      int toff = ks * 32 + lq * 8;
      u16x8 af = *(const u16x8*)(&BmT[(w * 16 + l16) * 72 + toff]);
#pragma unroll
      for (int pf = 0; pf < 4; ++pf) {
        u16x8 bfr = *(const u16x8*)(&Xt[(pf * 16 + l16) * 264 + part * 64 + toff]);
        accS[pf] = mfma16(af, bfr, accS[pf]);
      }
    }
  }
  unsigned short* Sp = statesb + (size_t)((b * 8 + c) * 64 + h) * 8192;
#pragma unroll
  for (int pf = 0; pf < 4; ++pf) {
    u16x4 hh = {f2bf(accS[pf][0]), f2bf(accS[pf][1]), f2bf(accS[pf][2]),
                f2bf(accS[pf][3])};
    *(u16x4*)(&Sp[(pf * 16 + l16) * 128 + w * 16 + lq * 4]) = hh;
  }
}

// ---------------------------------------------------------------------------
// Sequential chunk scan -> prefix states (bf16, [p][n]); grid (h, b)
// ---------------------------------------------------------------------------
__global__ __launch_bounds__(256) void scan_states(
    const unsigned short* __restrict__ statesb, const float* __restrict__ Acs,
    unsigned short* __restrict__ prefix) {
  const int h = blockIdx.x, b = blockIdx.y;
  const int tid = threadIdx.x;
  const int p = tid >> 2, nq = (tid & 3) * 32;
  float S[32];
#pragma unroll
  for (int i = 0; i < 32; ++i) S[i] = 0.0f;
  for (int cc = 0; cc < 8; ++cc) {
    size_t base = (size_t)((b * 8 + cc) * 64 + h) * 8192 + p * 128 + nq;
#pragma unroll
    for (int j = 0; j < 4; ++j) {
      u16x8 hh;
#pragma unroll
      for (int k = 0; k < 8; ++k) hh[k] = f2bf(S[j * 8 + k]);
      *(u16x8*)(prefix + base + j * 8) = hh;
    }
    float eAl = __expf(Acs[((size_t)((b * 64 + h) * 8 + cc)) * 256 + 255]);
#pragma unroll
    for (int j = 0; j < 4; ++j) {
      u16x8 v = *(const u16x8*)(statesb + base + j * 8);
#pragma unroll
      for (int k = 0; k < 8; ++k) S[j * 8 + k] = eAl * S[j * 8 + k] + bf2f(v[k]);
    }
  }
}

// ---------------------------------------------------------------------------
// Fused Y: Y_diag (G.*L @ X) + Y_off (exp(Acs)*Cm @ P^T) + D*xh -> y bf16
// ---------------------------------------------------------------------------
__global__ __launch_bounds__(512) void ssd_main(
    const unsigned short* __restrict__ xbc, const float* __restrict__ dtb,
    const float* __restrict__ Acs, const float* __restrict__ G,
    const unsigned short* __restrict__ prefix, const float* __restrict__ Dv,
    unsigned short* __restrict__ y) {
  __shared__ __align__(16) unsigned short Xt[64 * 264];
  __shared__ float As_s[256];
  const int h = blockIdx.x, c = blockIdx.y, b = blockIdx.z;
  const int tid = threadIdx.x;
  const int lane = tid & 63, w = tid >> 6;
  const int l16 = lane & 15, lq = lane >> 4;
  const int row0 = b * 2048 + c * 256;

  if (tid < 256) As_s[tid] = Acs[((size_t)((b * 64 + h) * 8 + c)) * 256 + tid];
#pragma unroll
  for (int it = 0; it < 2; ++it) {
    int pb = tid & 15;
    int tb = it * 32 + (tid >> 4);
    float rr[4][4];
#pragma unroll
    for (int i = 0; i < 4; ++i) {
      int row = row0 + tb * 4 + i;
      u16x4 v = *(const u16x4*)(xbc + (size_t)row * 4352 + h * 64 + pb * 4);
      float dtv = dtb[(size_t)row * 64 + h];
#pragma unroll
      for (int j = 0; j < 4; ++j) rr[i][j] = bf2f(v[j]) * dtv;
    }
#pragma unroll
    for (int j = 0; j < 4; ++j) {
      u16x4 hh = {f2bf(rr[0][j]), f2bf(rr[1][j]), f2bf(rr[2][j]), f2bf(rr[3][j])};
      *(u16x4*)(&Xt[(pb * 4 + j) * 264 + tb * 4]) = hh;
    }
  }
  __syncthreads();

  f32x4 acc[2][4] = {};
  const float* Gt = G + (size_t)(b * 8 + c) * 65536;
  for (int ks = 0; ks < 8; ++ks) {
    const int tb = ks * 32 + lq * 8;
    u16x8 bfr[4];
#pragma unroll
    for (int pf = 0; pf < 4; ++pf)
      bfr[pf] = *(const u16x8*)(&Xt[(pf * 16 + l16) * 264 + tb]);
#pragma unroll
    for (int mf = 0; mf < 2; ++mf) {
      const int i = w * 32 + mf * 16 + l16;
      const float ai = As_s[i];
      const float* gp = Gt + i * 256 + tb;
      f32x4 g0 = *(const f32x4*)gp;
      f32x4 g1 = *(const f32x4*)(gp + 4);
      u16x8 af;
#pragma unroll
      for (int jj = 0; jj < 8; ++jj) {
        int j = tb + jj;
        float g = (jj < 4) ? g0[jj] : g1[jj - 4];
        float v = (i >= j) ? g * __expf(ai - As_s[j]) : 0.0f;
        af[jj] = f2bf(v);
      }
#pragma unroll
      for (int pf = 0; pf < 4; ++pf)
        acc[mf][pf] = mfma16(af, bfr[pf], acc[mf][pf]);
    }
  }
  const unsigned short* Pf = prefix + (size_t)((b * 8 + c) * 64 + h) * 8192;
  for (int ks = 0; ks < 4; ++ks) {
    const int nb = ks * 32 + lq * 8;
    u16x8 bfr[4];
#pragma unroll
    for (int pf = 0; pf < 4; ++pf)
      bfr[pf] = *(const u16x8*)(Pf + (size_t)(pf * 16 + l16) * 128 + nb);
#pragma unroll
    for (int mf = 0; mf < 2; ++mf) {
      const int i = w * 32 + mf * 16 + l16;
      const float eAi = __expf(As_s[i]);
      u16x8 cv = *(const u16x8*)(xbc + (size_t)(row0 + i) * 4352 + 4224 + nb);
      u16x8 af;
#pragma unroll
      for (int jj = 0; jj < 8; ++jj) af[jj] = f2bf(bf2f(cv[jj]) * eAi);
#pragma unroll
      for (int pf = 0; pf < 4; ++pf)
        acc[mf][pf] = mfma16(af, bfr[pf], acc[mf][pf]);
    }
  }
  const float Dh = Dv[h];
#pragma unroll
  for (int mf = 0; mf < 2; ++mf) {
#pragma unroll
    for (int r = 0; r < 4; ++r) {
      int t = w * 32 + mf * 16 + lq * 4 + r;
      size_t row = (size_t)(row0 + t);
#pragma unroll
      for (int pf = 0; pf < 4; ++pf) {
        int p = pf * 16 + l16;
        float xh = bf2f(xbc[row * 4352 + h * 64 + p]);
        y[row * 4096 + h * 64 + p] = f2bf(acc[mf][pf][r] + Dh * xh);
      }
    }
  }
}

// ---------------------------------------------------------------------------
// In-place: y = rmsnorm(y * silu(z)) * norm_w  (bf16)
// ---------------------------------------------------------------------------
__global__ __launch_bounds__(256) void norm_kernel(
    unsigned short* __restrict__ y, const unsigned short* __restrict__ zbf,
    const float* __restrict__ nw) {
  const int row = blockIdx.x, tid = threadIdx.x;
  unsigned short* yr = y + (size_t)row * 4096;
  const unsigned short* zr = zbf + (size_t)row * 4096;
  float vals[16];
  float ss = 0.0f;
#pragma unroll
  for (int i = 0; i < 2; ++i) {
    int cb = i * 2048 + tid * 8;
    u16x8 yv = *(const u16x8*)(yr + cb);
    u16x8 zv = *(const u16x8*)(zr + cb);
#pragma unroll
    for (int j = 0; j < 8; ++j) {
      float z = bf2f(zv[j]);
      float g = bf2f(yv[j]) * (z / (1.0f + __expf(-z)));
      vals[i * 8 + j] = g;
      ss += g * g;
    }
  }
#pragma unroll
  for (int off = 32; off > 0; off >>= 1) ss += __shfl_xor(ss, off, 64);
  __shared__ float red[4];
  if ((tid & 63) == 0) red[tid >> 6] = ss;
  __syncthreads();
  float tot = red[0] + red[1] + red[2] + red[3];
  float rr = rsqrtf(tot * (1.0f / 4096.0f) + 1e-5f);
#pragma unroll
  for (int i = 0; i < 2; ++i) {
    int cb = i * 2048 + tid * 8;
    f32x4 w0 = *(const f32x4*)(nw + cb);
    f32x4 w1 = *(const f32x4*)(nw + cb + 4);
    u16x8 o;
#pragma unroll
    for (int j = 0; j < 8; ++j) {
      float wv = (j < 4) ? w0[j] : w1[j - 4];
      o[j] = f2bf(vals[i * 8 + j] * rr * wv);
    }
    *(u16x8*)(yr + cb) = o;
  }
}

// ---------------------------------------------------------------------------
extern "C" void kernel_launch(void* const* d_in, const int* in_sizes, int n_in,
                              void* d_out, int out_size, void* d_ws,
                              size_t ws_size, hipStream_t stream) {
  const float* x = (const float*)d_in[0];
  const float* w_in = (const float*)d_in[1];
  const float* conv_w = (const float*)d_in[2];
  const float* conv_b = (const float*)d_in[3];
  const float* dt_bias = (const float*)d_in[4];
  const float* A_log = (const float*)d_in[5];
  const float* Dvec = (const float*)d_in[6];
  const float* norm_w = (const float*)d_in[7];
  const float* w_out = (const float*)d_in[8];
  float* out = (float*)d_out;

  char* w = (char*)d_ws;
  unsigned short* zbf = (unsigned short*)(w + 0);            // 33,554,432
  unsigned short* xbc = (unsigned short*)(w + 33554432);     // 35,651,584
  unsigned short* xbcraw = (unsigned short*)(w + 69206016);  // 35,651,584 (→prefix)
  float* dtb = (float*)(w + 104857600);                      // 1,048,576
  float* Acs = (float*)(w + 105906176);                      // 1,048,576
  float* G = (float*)(w + 106954752);                        // 4,194,304
  unsigned short* statesb = (unsigned short*)(w + 111149056);// 16,777,216
  unsigned short* y = (unsigned short*)(w + 127926272);      // 33,554,432
  // aliases (lifetimes disjoint, single stream):
  unsigned short* xbf = (unsigned short*)(w + 111149056);    // = statesb region
  unsigned short* w_inT = (unsigned short*)(w + 33554432);   // = xbc region (8704x2048)
  unsigned short* w_outT = (unsigned short*)(w + 33554432);  // = xbc region (2048x4096)
  unsigned short* prefix = xbcraw;

  convert_bf16<<<dim3(4096), 256, 0, stream>>>(x, xbf);
  transpose_conv<<<dim3(136, 32), 256, 0, stream>>>(w_in, w_inT, 2048, 8512);
  gemm8_in<<<dim3(34, 16), 512, 0, stream>>>(xbf, w_inT, zbf, xbcraw, dtb);
  conv_kernel<<<dim3(5, 1024), 256, 0, stream>>>(xbcraw, conv_w, conv_b, xbc);
  dt_kernel<<<dim3(1024), 256, 0, stream>>>(dtb, dt_bias, A_log, Acs);
  g_kernel<<<dim3(16, 16), 256, 0, stream>>>(xbc, G);
  ssd_states<<<dim3(64, 8, 2), 512, 0, stream>>>(xbc, dtb, Acs, statesb);
  scan_states<<<dim3(64, 2), 256, 0, stream>>>(statesb, Acs, prefix);
  ssd_main<<<dim3(64, 8, 2), 512, 0, stream>>>(xbc, dtb, Acs, G, prefix, Dvec, y);
  transpose_conv<<<dim3(32, 64), 256, 0, stream>>>(w_out, w_outT, 4096, 2048);
  norm_kernel<<<dim3(4096), 256, 0, stream>>>(y, zbf, norm_w);
  gemm_p<<<dim3(16, 32), 256, 0, stream>>>(y, w_outT, 4096, out, x);
}

// Round 13
// 460.651 us; speedup vs baseline: 1.1395x; 1.1395x over previous
//
#include <hip/hip_runtime.h>
#include <math.h>

#define DEV __device__ __forceinline__

typedef __attribute__((ext_vector_type(4))) float f32x4;
typedef __attribute__((ext_vector_type(4))) unsigned short u16x4;
typedef __attribute__((ext_vector_type(8))) unsigned short u16x8;
typedef __attribute__((ext_vector_type(8))) __bf16 bfv8;

DEV unsigned short f2bf(float f) {
  unsigned u = __builtin_bit_cast(unsigned, f);
  u = (u + 0x7FFFu + ((u >> 16) & 1u)) >> 16;
  return (unsigned short)u;
}
DEV float bf2f(unsigned short h) {
  unsigned u = ((unsigned)h) << 16;
  return __builtin_bit_cast(float, u);
}

DEV f32x4 mfma16(u16x8 a, u16x8 b, f32x4 c) {
  return __builtin_amdgcn_mfma_f32_16x16x32_bf16(
      __builtin_bit_cast(bfv8, a), __builtin_bit_cast(bfv8, b), c, 0, 0, 0);
}

DEV void gload_lds16(const unsigned short* g, unsigned short* s) {
  __builtin_amdgcn_global_load_lds(
      (const __attribute__((address_space(1))) void*)g,
      (__attribute__((address_space(3))) void*)s, 16, 0, 0);
}

template <int N>
DEV void vmcnt_wait() {
  if constexpr (N == 0) asm volatile("s_waitcnt vmcnt(0)" ::: "memory");
  else if constexpr (N == 2) asm volatile("s_waitcnt vmcnt(2)" ::: "memory");
  else if constexpr (N == 4) asm volatile("s_waitcnt vmcnt(4)" ::: "memory");
}

// ---------------------------------------------------------------------------
// 8-phase 256x256 bf16 GEMM (R8 proven: 196 us, MfmaUtil 31.4), in_proj.
// K=2048, BK=64, 512 thr / 8 waves (4M x 2N), 2-deep LDS dbuf (128 KB).
// 4 phases/K-tile, 16 MFMA each; slot-staggered prefetch with counted
// vmcnt(4)/vmcnt(2) (never 0 in steady state). XOR chunk swizzle.
// ---------------------------------------------------------------------------
__global__ __launch_bounds__(512, 2) void gemm8_in(
    const unsigned short* __restrict__ A, const unsigned short* __restrict__ Bt,
    unsigned short* __restrict__ o_z, unsigned short* __restrict__ o_xbc,
    float* __restrict__ o_dt) {
  constexpr int K = 2048, NT = K / 64;
  __shared__ __align__(16) unsigned short As[2][256 * 64];
  __shared__ __align__(16) unsigned short Bs[2][256 * 64];
  const int tid = threadIdx.x;
  const int lane = tid & 63, w = tid >> 6;
  const int l16 = lane & 15, lq = lane >> 4;
  const int wr = w >> 1, wc = w & 1;
  const int nwg = gridDim.x * gridDim.y;
  int lin = blockIdx.y * gridDim.x + blockIdx.x;
  lin = (lin & 7) * (nwg >> 3) + (lin >> 3);
  const int m0 = (lin / gridDim.x) * 256, n0 = (lin % gridDim.x) * 256;
  const int srow = lane >> 3;
  const int schk = (lane & 7) ^ srow;
  const unsigned short* Ag = A + (size_t)(m0 + srow) * K + schk * 8;
  const unsigned short* Bg = Bt + (size_t)(n0 + srow) * K + schk * 8;
  const int px0 = lq ^ (l16 & 7);
  const int px1 = (4 + lq) ^ (l16 & 7);

  f32x4 acc[4][8] = {};

  auto stageA = [&](int p, int slot, int kt) {
    gload_lds16(Ag + (size_t)(slot * 64 + w * 8) * K + kt * 64,
                &As[p][(slot * 64 + w * 8) * 64]);
  };
  auto stageB = [&](int p, int slot, int kt) {
    gload_lds16(Bg + (size_t)(slot * 64 + w * 8) * K + kt * 64,
                &Bs[p][(slot * 64 + w * 8) * 64]);
  };
  auto rdA = [&](int p, int mf, int k2) -> u16x8 {
    const int row = wr * 64 + mf * 16 + l16;
    return *(const u16x8*)(&As[p][row * 64 + (k2 ? px1 : px0) * 8]);
  };
  auto rdB = [&](int p, int nf, int k2) -> u16x8 {
    const int row = wc * 128 + nf * 16 + l16;
    return *(const u16x8*)(&Bs[p][row * 64 + (k2 ? px1 : px0) * 8]);
  };

  stageA(0, 0, 0); stageA(0, 1, 0); stageA(0, 2, 0); stageA(0, 3, 0);
  stageB(0, 0, 0); stageB(0, 2, 0); stageB(0, 1, 0); stageB(0, 3, 0);
  vmcnt_wait<2>();
  __builtin_amdgcn_s_barrier();

  u16x8 a0[4], a1[4], b0[2], b1[2];
  for (int k = 0; k < NT; ++k) {
    const int p = k & 1, pn = p ^ 1;
    const bool st = (k + 1 < NT);
#pragma unroll
    for (int mf = 0; mf < 4; ++mf) { a0[mf] = rdA(p, mf, 0); a1[mf] = rdA(p, mf, 1); }
    b0[0] = rdB(p, 0, 0); b1[0] = rdB(p, 0, 1);
    b0[1] = rdB(p, 1, 0); b1[1] = rdB(p, 1, 1);
    if (st) { stageA(pn, 0, k + 1); stageA(pn, 1, k + 1); }
    __builtin_amdgcn_s_barrier();
    __builtin_amdgcn_s_setprio(1);
#pragma unroll
    for (int nf = 0; nf < 2; ++nf)
#pragma unroll
      for (int mf = 0; mf < 4; ++mf) {
        acc[mf][nf] = mfma16(a0[mf], b0[nf], acc[mf][nf]);
        acc[mf][nf] = mfma16(a1[mf], b1[nf], acc[mf][nf]);
      }
    __builtin_amdgcn_s_setprio(0);
    __builtin_amdgcn_s_barrier();
    b0[0] = rdB(p, 2, 0); b1[0] = rdB(p, 2, 1);
    b0[1] = rdB(p, 3, 0); b1[1] = rdB(p, 3, 1);
    if (st) { stageA(pn, 2, k + 1); stageA(pn, 3, k + 1); vmcnt_wait<4>(); }
    else vmcnt_wait<0>();
    __builtin_amdgcn_s_barrier();
    __builtin_amdgcn_s_setprio(1);
#pragma unroll
    for (int nf = 0; nf < 2; ++nf)
#pragma unroll
      for (int mf = 0; mf < 4; ++mf) {
        acc[mf][2 + nf] = mfma16(a0[mf], b0[nf], acc[mf][2 + nf]);
        acc[mf][2 + nf] = mfma16(a1[mf], b1[nf], acc[mf][2 + nf]);
      }
    __builtin_amdgcn_s_setprio(0);
    __builtin_amdgcn_s_barrier();
    b0[0] = rdB(p, 4, 0); b1[0] = rdB(p, 4, 1);
    b0[1] = rdB(p, 5, 0); b1[1] = rdB(p, 5, 1);
    if (st) { stageB(pn, 0, k + 1); stageB(pn, 2, k + 1); }
    __builtin_amdgcn_s_barrier();
    __builtin_amdgcn_s_setprio(1);
#pragma unroll
    for (int nf = 0; nf < 2; ++nf)
#pragma unroll
      for (int mf = 0; mf < 4; ++mf) {
        acc[mf][4 + nf] = mfma16(a0[mf], b0[nf], acc[mf][4 + nf]);
        acc[mf][4 + nf] = mfma16(a1[mf], b1[nf], acc[mf][4 + nf]);
      }
    __builtin_amdgcn_s_setprio(0);
    __builtin_amdgcn_s_barrier();
    b0[0] = rdB(p, 6, 0); b1[0] = rdB(p, 6, 1);
    b0[1] = rdB(p, 7, 0); b1[1] = rdB(p, 7, 1);
    if (st) { stageB(pn, 1, k + 1); stageB(pn, 3, k + 1); vmcnt_wait<2>(); }
    else vmcnt_wait<0>();
    __builtin_amdgcn_s_barrier();
    __builtin_amdgcn_s_setprio(1);
#pragma unroll
    for (int nf = 0; nf < 2; ++nf)
#pragma unroll
      for (int mf = 0; mf < 4; ++mf) {
        acc[mf][6 + nf] = mfma16(a0[mf], b0[nf], acc[mf][6 + nf]);
        acc[mf][6 + nf] = mfma16(a1[mf], b1[nf], acc[mf][6 + nf]);
      }
    __builtin_amdgcn_s_setprio(0);
    __builtin_amdgcn_s_barrier();
  }

#pragma unroll
  for (int mf = 0; mf < 4; ++mf) {
#pragma unroll
    for (int nf = 0; nf < 8; ++nf) {
      const int col = n0 + wc * 128 + nf * 16 + l16;
#pragma unroll
      for (int r = 0; r < 4; ++r) {
        const int row = m0 + wr * 64 + mf * 16 + lq * 4 + r;
        float v = acc[mf][nf][r];
        if (col < 4096) o_z[(size_t)row * 4096 + col] = f2bf(v);
        else if (col < 8448) o_xbc[(size_t)row * 4352 + (col - 4096)] = f2bf(v);
        else if (col < 8512) o_dt[(size_t)row * 64 + (col - 8448)] = v;
      }
    }
  }
}

// ---------------------------------------------------------------------------
// Pipelined bf16 GEMM (R7/R8 structure) for out_proj: 128x128, 4 waves,
// BK=32, 3-buffer ring, counted vmcnt(4). += resid -> f32 (N=2048).
// ---------------------------------------------------------------------------
__global__ __launch_bounds__(256, 3) void gemm_p(
    const unsigned short* __restrict__ A, const unsigned short* __restrict__ Bt,
    int K, float* __restrict__ o_c, const float* __restrict__ resid) {
  __shared__ __align__(16) unsigned short As[3][128 * 32];
  __shared__ __align__(16) unsigned short Bs[3][128 * 32];
  const int tid = threadIdx.x;
  const int lane = tid & 63, w = tid >> 6;
  const int l16 = lane & 15, lq = lane >> 4;
  const int wr = w >> 1, wc = w & 1;
  const int nwg = gridDim.x * gridDim.y;
  int lin = blockIdx.y * gridDim.x + blockIdx.x;
  lin = (lin & 7) * (nwg >> 3) + (lin >> 3);
  const int m0 = (lin / gridDim.x) * 128, n0 = (lin % gridDim.x) * 128;
  const int lrow = lane >> 2;
  const int gq = (lane & 3) ^ ((lrow >> 1) & 3);
  const int cq = lq ^ ((l16 >> 1) & 3);

  const unsigned short* Ag = A + (size_t)(m0 + lrow) * K + gq * 8;
  const unsigned short* Bg = Bt + (size_t)(n0 + lrow) * K + gq * 8;

  f32x4 acc[4][4] = {};

  auto stage = [&](int bi, int kt) {
#pragma unroll
    for (int i = 0; i < 2; ++i) {
      const int rb = (w + i * 4) * 16;
      gload_lds16(Ag + (size_t)rb * K + kt * 32, &As[bi][rb * 32]);
    }
#pragma unroll
    for (int i = 0; i < 2; ++i) {
      const int rb = (w + i * 4) * 16;
      gload_lds16(Bg + (size_t)rb * K + kt * 32, &Bs[bi][rb * 32]);
    }
  };

  const int nt = K / 32;
  stage(0, 0);
  stage(1, 1);

  for (int k = 0; k < nt; ++k) {
    const int cb = k % 3;
    if (k < nt - 1) vmcnt_wait<4>();
    else vmcnt_wait<0>();
    __builtin_amdgcn_s_barrier();
    if (k + 2 < nt) stage((k + 2) % 3, k + 2);

    u16x8 af[4], bf[4];
#pragma unroll
    for (int mf = 0; mf < 4; ++mf)
      af[mf] = *(const u16x8*)(&As[cb][(wr * 64 + mf * 16 + l16) * 32 + cq * 8]);
#pragma unroll
    for (int nf = 0; nf < 4; ++nf)
      bf[nf] = *(const u16x8*)(&Bs[cb][(wc * 64 + nf * 16 + l16) * 32 + cq * 8]);

    __builtin_amdgcn_s_setprio(1);
#pragma unroll
    for (int mf = 0; mf < 4; ++mf)
#pragma unroll
      for (int nf = 0; nf < 4; ++nf)
        acc[mf][nf] = mfma16(af[mf], bf[nf], acc[mf][nf]);
    __builtin_amdgcn_s_setprio(0);
  }

#pragma unroll
  for (int mf = 0; mf < 4; ++mf) {
#pragma unroll
    for (int nf = 0; nf < 4; ++nf) {
      const int col = n0 + wc * 64 + nf * 16 + l16;
#pragma unroll
      for (int r = 0; r < 4; ++r) {
        const int row = m0 + wr * 64 + mf * 16 + lq * 4 + r;
        size_t idx = (size_t)row * 2048 + col;
        o_c[idx] = acc[mf][nf][r] + resid[idx];
      }
    }
  }
}

// ---------------------------------------------------------------------------
// Prep: region A converts x f32->bf16 (blocks 0..4095, 8 elems/thread);
// region B transposes w_in [2048][8512] -> w_inT [8704][2048] bf16
// (blocks 4096..8447 = 136x32 tiles). Block-uniform branch.
// ---------------------------------------------------------------------------
__global__ __launch_bounds__(256) void prep_kernel(
    const float* __restrict__ x, unsigned short* __restrict__ xbf,
    const float* __restrict__ w_in, unsigned short* __restrict__ w_inT) {
  __shared__ __align__(16) unsigned short T[64][72];
  const int b = blockIdx.x;
  const int tid = threadIdx.x;
  if (b < 4096) {
    const size_t i = ((size_t)b * 256 + tid) * 8;
    f32x4 a = *(const f32x4*)(x + i);
    f32x4 c = *(const f32x4*)(x + i + 4);
    u16x8 o;
#pragma unroll
    for (int j = 0; j < 4; ++j) { o[j] = f2bf(a[j]); o[j + 4] = f2bf(c[j]); }
    *(u16x8*)(xbf + i) = o;
  } else {
    const int idx = b - 4096;
    const int c0 = (idx % 136) * 64, r0 = (idx / 136) * 64;
#pragma unroll
    for (int it = 0; it < 4; ++it) {
      int r = it * 16 + (tid >> 4);
      int c = (tid & 15) * 4;
      f32x4 v = {0.f, 0.f, 0.f, 0.f};
      if (c0 + c < 8512) v = *(const f32x4*)(w_in + (size_t)(r0 + r) * 8512 + c0 + c);
#pragma unroll
      for (int j = 0; j < 4; ++j) T[c + j][r] = f2bf(v[j]);
    }
    __syncthreads();
    const int nr = tid >> 2, kc = (tid & 3) * 16;
    u16x8 a = *(const u16x8*)(&T[nr][kc]);
    u16x8 c = *(const u16x8*)(&T[nr][kc + 8]);
    unsigned short* o = w_inT + (size_t)(c0 + nr) * 2048 + r0 + kc;
    *(u16x8*)o = a;
    *(u16x8*)(o + 8) = c;
  }
}

// ---------------------------------------------------------------------------
// transpose+convert (used late for w_out): in[R][C] f32 -> out[C][R] bf16
// ---------------------------------------------------------------------------
__global__ __launch_bounds__(256) void transpose_conv(
    const float* __restrict__ in, unsigned short* __restrict__ out, int R,
    int C) {
  __shared__ __align__(16) unsigned short T[64][72];
  const int c0 = blockIdx.x * 64, r0 = blockIdx.y * 64;
  const int tid = threadIdx.x;
#pragma unroll
  for (int it = 0; it < 4; ++it) {
    int r = it * 16 + (tid >> 4);
    int c = (tid & 15) * 4;
    f32x4 v = {0.f, 0.f, 0.f, 0.f};
    if (c0 + c < C) v = *(const f32x4*)(in + (size_t)(r0 + r) * C + c0 + c);
#pragma unroll
    for (int j = 0; j < 4; ++j) T[c + j][r] = f2bf(v[j]);
  }
  __syncthreads();
  const int nr = tid >> 2, kc = (tid & 3) * 16;
  u16x8 a = *(const u16x8*)(&T[nr][kc]);
  u16x8 b = *(const u16x8*)(&T[nr][kc + 8]);
  unsigned short* o = out + (size_t)(c0 + nr) * R + r0 + kc;
  *(u16x8*)o = a;
  *(u16x8*)(o + 8) = b;
}

// ---------------------------------------------------------------------------
// Fused conv + dt. Blocks 0..5119: depthwise causal conv (L-tiled x4) +
// bias + SiLU. Blocks 5120..6143: dt softplus + per-chunk shuffle cumsum.
// ---------------------------------------------------------------------------
__global__ __launch_bounds__(256) void convdt_kernel(
    const unsigned short* __restrict__ raw, const float* __restrict__ cw,
    const float* __restrict__ cb, unsigned short* __restrict__ xbc,
    float* __restrict__ dtb, const float* __restrict__ dt_bias,
    const float* __restrict__ A_log, float* __restrict__ Acs) {
  __shared__ float wsum[4];
  const int b = blockIdx.x;
  const int tid = threadIdx.x;
  if (b < 5120) {
    const int ch4 = (b % 5) * 256 + tid;
    if (ch4 >= 1088) return;
    const int ch = ch4 * 4;
    const int r0 = (b / 5) * 4;
    const int l0 = r0 & 2047;
    f32x4 w0 = *(const f32x4*)(cw + ch * 4);
    f32x4 w1 = *(const f32x4*)(cw + ch * 4 + 4);
    f32x4 w2 = *(const f32x4*)(cw + ch * 4 + 8);
    f32x4 w3 = *(const f32x4*)(cw + ch * 4 + 12);
    f32x4 bias = *(const f32x4*)(cb + ch);
    f32x4 v[7];
#pragma unroll
    for (int i = 0; i < 7; ++i) {
      if (l0 - 3 + i >= 0) {
        u16x4 h = *(const u16x4*)(raw + (size_t)(r0 - 3 + i) * 4352 + ch);
        v[i] = (f32x4){bf2f(h[0]), bf2f(h[1]), bf2f(h[2]), bf2f(h[3])};
      } else {
        v[i] = (f32x4){0.f, 0.f, 0.f, 0.f};
      }
    }
#pragma unroll
    for (int j = 0; j < 4; ++j) {
      f32x4 acc = bias;
#pragma unroll
      for (int k = 0; k < 4; ++k) {
        acc[0] += w0[k] * v[j + k][0];
        acc[1] += w1[k] * v[j + k][1];
        acc[2] += w2[k] * v[j + k][2];
        acc[3] += w3[k] * v[j + k][3];
      }
      u16x4 o;
#pragma unroll
      for (int q = 0; q < 4; ++q) {
        float s = acc[q] / (1.0f + __expf(-acc[q]));
        o[q] = f2bf(s);
      }
      *(u16x4*)(xbc + (size_t)(r0 + j) * 4352 + ch) = o;
    }
  } else {
    const int blk = b - 5120;
    const int c = blk & 7, h = (blk >> 3) & 63, bb = blk >> 9;
    const int lane = tid & 63, w = tid >> 6;
    const int row = bb * 2048 + c * 256 + tid;
    float xv = dtb[(size_t)row * 64 + h] + dt_bias[h];
    float dt = (xv > 20.0f) ? xv : log1pf(__expf(xv));
    dtb[(size_t)row * 64 + h] = dt;
    float s = dt * (-__expf(A_log[h]));
#pragma unroll
    for (int off = 1; off < 64; off <<= 1) {
      float v = __shfl_up(s, off, 64);
      if (lane >= off) s += v;
    }
    if (lane == 63) wsum[w] = s;
    __syncthreads();
    float base = 0.0f;
#pragma unroll
    for (int i = 0; i < 4; ++i)
      if (i < w) base += wsum[i];
    Acs[((size_t)((bb * 64 + h) * 8 + c)) * 256 + tid] = s + base;
  }
}

// ---------------------------------------------------------------------------
// G[bc][i][j] = sum_n Cm[i][n]*Bm[j][n] (head-independent)
// ---------------------------------------------------------------------------
__global__ __launch_bounds__(256) void g_kernel(
    const unsigned short* __restrict__ xbc, float* __restrict__ G) {
  const int bc = blockIdx.y;
  const int i0 = (blockIdx.x >> 2) * 64, j0 = (blockIdx.x & 3) * 64;
  const int tid = threadIdx.x;
  const int lane = tid & 63, w = tid >> 6;
  const int l16 = lane & 15, lq = lane >> 4;
  const unsigned short* base = xbc + (size_t)bc * 256 * 4352;
  f32x4 acc[4] = {};
#pragma unroll
  for (int ks = 0; ks < 4; ++ks) {
    int nb = ks * 32 + lq * 8;
    u16x8 af = *(const u16x8*)(base + (size_t)(i0 + w * 16 + l16) * 4352 + 4224 + nb);
#pragma unroll
    for (int jf = 0; jf < 4; ++jf) {
      u16x8 bb = *(const u16x8*)(base + (size_t)(j0 + jf * 16 + l16) * 4352 + 4096 + nb);
      acc[jf] = mfma16(af, bb, acc[jf]);
    }
  }
  float* Gt = G + (size_t)bc * 65536;
#pragma unroll
  for (int jf = 0; jf < 4; ++jf)
#pragma unroll
    for (int r = 0; r < 4; ++r)
      Gt[(i0 + w * 16 + lq * 4 + r) * 256 + j0 + jf * 16 + l16] = acc[jf][r];
}

// ---------------------------------------------------------------------------
// Per-chunk states: states[p][n] (bf16) = sum_t Bm[t][n]*decay(t)*X[t][p]
// ---------------------------------------------------------------------------
__global__ __launch_bounds__(512) void ssd_states(
    const unsigned short* __restrict__ xbc, const float* __restrict__ dtb,
    const float* __restrict__ Acs, unsigned short* __restrict__ statesb) {
  __shared__ __align__(16) unsigned short Xt[64 * 264];
  __shared__ __align__(16) unsigned short BmT[128 * 72];
  __shared__ float As_s[256];
  const int h = blockIdx.x, c = blockIdx.y, b = blockIdx.z;
  const int tid = threadIdx.x;
  const int lane = tid & 63, w = tid >> 6;
  const int l16 = lane & 15, lq = lane >> 4;
  const int row0 = b * 2048 + c * 256;

  if (tid < 256) As_s[tid] = Acs[((size_t)((b * 64 + h) * 8 + c)) * 256 + tid];
#pragma unroll
  for (int it = 0; it < 2; ++it) {
    int pb = tid & 15;
    int tb = it * 32 + (tid >> 4);
    float rr[4][4];
#pragma unroll
    for (int i = 0; i < 4; ++i) {
      int row = row0 + tb * 4 + i;
      u16x4 v = *(const u16x4*)(xbc + (size_t)row * 4352 + h * 64 + pb * 4);
      float dtv = dtb[(size_t)row * 64 + h];
#pragma unroll
      for (int j = 0; j < 4; ++j) rr[i][j] = bf2f(v[j]) * dtv;
    }
#pragma unroll
    for (int j = 0; j < 4; ++j) {
      u16x4 hh = {f2bf(rr[0][j]), f2bf(rr[1][j]), f2bf(rr[2][j]), f2bf(rr[3][j])};
      *(u16x4*)(&Xt[(pb * 4 + j) * 264 + tb * 4]) = hh;
    }
  }
  __syncthreads();

  f32x4 accS[4] = {};
  const float Alast = As_s[255];
  for (int part = 0; part < 4; ++part) {
    if (part) __syncthreads();
    {
      int nb = tid & 31;
      int tb = tid >> 5;
      float rr[4][4];
#pragma unroll
      for (int i = 0; i < 4; ++i) {
        int t = part * 64 + tb * 4 + i;
        int row = row0 + t;
        float dec = __expf(Alast - As_s[t]);
        u16x4 v = *(const u16x4*)(xbc + (size_t)row * 4352 + 4096 + nb * 4);
#pragma unroll
        for (int j = 0; j < 4; ++j) rr[i][j] = bf2f(v[j]) * dec;
      }
#pragma unroll
      for (int j = 0; j < 4; ++j) {
        u16x4 hh = {f2bf(rr[0][j]), f2bf(rr[1][j]), f2bf(rr[2][j]), f2bf(rr[3][j])};
        *(u16x4*)(&BmT[(nb * 4 + j) * 72 + tb * 4]) = hh;
      }
    }
    __syncthreads();
#pragma unroll
    for (int ks = 0; ks < 2; ++ks) {
      int toff = ks * 32 + lq * 8;
      u16x8 af = *(const u16x8*)(&BmT[(w * 16 + l16) * 72 + toff]);
#pragma unroll
      for (int pf = 0; pf < 4; ++pf) {
        u16x8 bfr = *(const u16x8*)(&Xt[(pf * 16 + l16) * 264 + part * 64 + toff]);
        accS[pf] = mfma16(af, bfr, accS[pf]);
      }
    }
  }
  unsigned short* Sp = statesb + (size_t)((b * 8 + c) * 64 + h) * 8192;
#pragma unroll
  for (int pf = 0; pf < 4; ++pf) {
    u16x4 hh = {f2bf(accS[pf][0]), f2bf(accS[pf][1]), f2bf(accS[pf][2]),
                f2bf(accS[pf][3])};
    *(u16x4*)(&Sp[(pf * 16 + l16) * 128 + w * 16 + lq * 4]) = hh;
  }
}

// ---------------------------------------------------------------------------
// Sequential chunk scan -> prefix states (bf16, [p][n]); grid (h, b)
// ---------------------------------------------------------------------------
__global__ __launch_bounds__(256) void scan_states(
    const unsigned short* __restrict__ statesb, const float* __restrict__ Acs,
    unsigned short* __restrict__ prefix) {
  const int h = blockIdx.x, b = blockIdx.y;
  const int tid = threadIdx.x;
  const int p = tid >> 2, nq = (tid & 3) * 32;
  float S[32];
#pragma unroll
  for (int i = 0; i < 32; ++i) S[i] = 0.0f;
  for (int cc = 0; cc < 8; ++cc) {
    size_t base = (size_t)((b * 8 + cc) * 64 + h) * 8192 + p * 128 + nq;
#pragma unroll
    for (int j = 0; j < 4; ++j) {
      u16x8 hh;
#pragma unroll
      for (int k = 0; k < 8; ++k) hh[k] = f2bf(S[j * 8 + k]);
      *(u16x8*)(prefix + base + j * 8) = hh;
    }
    float eAl = __expf(Acs[((size_t)((b * 64 + h) * 8 + cc)) * 256 + 255]);
#pragma unroll
    for (int j = 0; j < 4; ++j) {
      u16x8 v = *(const u16x8*)(statesb + base + j * 8);
#pragma unroll
      for (int k = 0; k < 8; ++k) S[j * 8 + k] = eAl * S[j * 8 + k] + bf2f(v[k]);
    }
  }
}

// ---------------------------------------------------------------------------
// Fused Y: Y_diag (G.*L @ X) + Y_off (exp(Acs)*Cm @ P^T) + D*xh -> y bf16
// ---------------------------------------------------------------------------
__global__ __launch_bounds__(512) void ssd_main(
    const unsigned short* __restrict__ xbc, const float* __restrict__ dtb,
    const float* __restrict__ Acs, const float* __restrict__ G,
    const unsigned short* __restrict__ prefix, const float* __restrict__ Dv,
    unsigned short* __restrict__ y) {
  __shared__ __align__(16) unsigned short Xt[64 * 264];
  __shared__ float As_s[256];
  const int h = blockIdx.x, c = blockIdx.y, b = blockIdx.z;
  const int tid = threadIdx.x;
  const int lane = tid & 63, w = tid >> 6;
  const int l16 = lane & 15, lq = lane >> 4;
  const int row0 = b * 2048 + c * 256;

  if (tid < 256) As_s[tid] = Acs[((size_t)((b * 64 + h) * 8 + c)) * 256 + tid];
#pragma unroll
  for (int it = 0; it < 2; ++it) {
    int pb = tid & 15;
    int tb = it * 32 + (tid >> 4);
    float rr[4][4];
#pragma unroll
    for (int i = 0; i < 4; ++i) {
      int row = row0 + tb * 4 + i;
      u16x4 v = *(const u16x4*)(xbc + (size_t)row * 4352 + h * 64 + pb * 4);
      float dtv = dtb[(size_t)row * 64 + h];
#pragma unroll
      for (int j = 0; j < 4; ++j) rr[i][j] = bf2f(v[j]) * dtv;
    }
#pragma unroll
    for (int j = 0; j < 4; ++j) {
      u16x4 hh = {f2bf(rr[0][j]), f2bf(rr[1][j]), f2bf(rr[2][j]), f2bf(rr[3][j])};
      *(u16x4*)(&Xt[(pb * 4 + j) * 264 + tb * 4]) = hh;
    }
  }
  __syncthreads();

  f32x4 acc[2][4] = {};
  const float* Gt = G + (size_t)(b * 8 + c) * 65536;
  for (int ks = 0; ks < 8; ++ks) {
    const int tb = ks * 32 + lq * 8;
    u16x8 bfr[4];
#pragma unroll
    for (int pf = 0; pf < 4; ++pf)
      bfr[pf] = *(const u16x8*)(&Xt[(pf * 16 + l16) * 264 + tb]);
#pragma unroll
    for (int mf = 0; mf < 2; ++mf) {
      const int i = w * 32 + mf * 16 + l16;
      const float ai = As_s[i];
      const float* gp = Gt + i * 256 + tb;
      f32x4 g0 = *(const f32x4*)gp;
      f32x4 g1 = *(const f32x4*)(gp + 4);
      u16x8 af;
#pragma unroll
      for (int jj = 0; jj < 8; ++jj) {
        int j = tb + jj;
        float g = (jj < 4) ? g0[jj] : g1[jj - 4];
        float v = (i >= j) ? g * __expf(ai - As_s[j]) : 0.0f;
        af[jj] = f2bf(v);
      }
#pragma unroll
      for (int pf = 0; pf < 4; ++pf)
        acc[mf][pf] = mfma16(af, bfr[pf], acc[mf][pf]);
    }
  }
  const unsigned short* Pf = prefix + (size_t)((b * 8 + c) * 64 + h) * 8192;
  for (int ks = 0; ks < 4; ++ks) {
    const int nb = ks * 32 + lq * 8;
    u16x8 bfr[4];
#pragma unroll
    for (int pf = 0; pf < 4; ++pf)
      bfr[pf] = *(const u16x8*)(Pf + (size_t)(pf * 16 + l16) * 128 + nb);
#pragma unroll
    for (int mf = 0; mf < 2; ++mf) {
      const int i = w * 32 + mf * 16 + l16;
      const float eAi = __expf(As_s[i]);
      u16x8 cv = *(const u16x8*)(xbc + (size_t)(row0 + i) * 4352 + 4224 + nb);
      u16x8 af;
#pragma unroll
      for (int jj = 0; jj < 8; ++jj) af[jj] = f2bf(bf2f(cv[jj]) * eAi);
#pragma unroll
      for (int pf = 0; pf < 4; ++pf)
        acc[mf][pf] = mfma16(af, bfr[pf], acc[mf][pf]);
    }
  }
  const float Dh = Dv[h];
#pragma unroll
  for (int mf = 0; mf < 2; ++mf) {
#pragma unroll
    for (int r = 0; r < 4; ++r) {
      int t = w * 32 + mf * 16 + lq * 4 + r;
      size_t row = (size_t)(row0 + t);
#pragma unroll
      for (int pf = 0; pf < 4; ++pf) {
        int p = pf * 16 + l16;
        float xh = bf2f(xbc[row * 4352 + h * 64 + p]);
        y[row * 4096 + h * 64 + p] = f2bf(acc[mf][pf][r] + Dh * xh);
      }
    }
  }
}

// ---------------------------------------------------------------------------
// In-place: y = rmsnorm(y * silu(z)) * norm_w  (bf16)
// ---------------------------------------------------------------------------
__global__ __launch_bounds__(256) void norm_kernel(
    unsigned short* __restrict__ y, const unsigned short* __restrict__ zbf,
    const float* __restrict__ nw) {
  const int row = blockIdx.x, tid = threadIdx.x;
  unsigned short* yr = y + (size_t)row * 4096;
  const unsigned short* zr = zbf + (size_t)row * 4096;
  float vals[16];
  float ss = 0.0f;
#pragma unroll
  for (int i = 0; i < 2; ++i) {
    int cb = i * 2048 + tid * 8;
    u16x8 yv = *(const u16x8*)(yr + cb);
    u16x8 zv = *(const u16x8*)(zr + cb);
#pragma unroll
    for (int j = 0; j < 8; ++j) {
      float z = bf2f(zv[j]);
      float g = bf2f(yv[j]) * (z / (1.0f + __expf(-z)));
      vals[i * 8 + j] = g;
      ss += g * g;
    }
  }
#pragma unroll
  for (int off = 32; off > 0; off >>= 1) ss += __shfl_xor(ss, off, 64);
  __shared__ float red[4];
  if ((tid & 63) == 0) red[tid >> 6] = ss;
  __syncthreads();
  float tot = red[0] + red[1] + red[2] + red[3];
  float rr = rsqrtf(tot * (1.0f / 4096.0f) + 1e-5f);
#pragma unroll
  for (int i = 0; i < 2; ++i) {
    int cb = i * 2048 + tid * 8;
    f32x4 w0 = *(const f32x4*)(nw + cb);
    f32x4 w1 = *(const f32x4*)(nw + cb + 4);
    u16x8 o;
#pragma unroll
    for (int j = 0; j < 8; ++j) {
      float wv = (j < 4) ? w0[j] : w1[j - 4];
      o[j] = f2bf(vals[i * 8 + j] * rr * wv);
    }
    *(u16x8*)(yr + cb) = o;
  }
}

// ---------------------------------------------------------------------------
extern "C" void kernel_launch(void* const* d_in, const int* in_sizes, int n_in,
                              void* d_out, int out_size, void* d_ws,
                              size_t ws_size, hipStream_t stream) {
  const float* x = (const float*)d_in[0];
  const float* w_in = (const float*)d_in[1];
  const float* conv_w = (const float*)d_in[2];
  const float* conv_b = (const float*)d_in[3];
  const float* dt_bias = (const float*)d_in[4];
  const float* A_log = (const float*)d_in[5];
  const float* Dvec = (const float*)d_in[6];
  const float* norm_w = (const float*)d_in[7];
  const float* w_out = (const float*)d_in[8];
  float* out = (float*)d_out;

  char* w = (char*)d_ws;
  unsigned short* zbf = (unsigned short*)(w + 0);            // 33,554,432
  unsigned short* xbc = (unsigned short*)(w + 33554432);     // 35,651,584
  unsigned short* xbcraw = (unsigned short*)(w + 69206016);  // 35,651,584 (→prefix)
  float* dtb = (float*)(w + 104857600);                      // 1,048,576
  float* Acs = (float*)(w + 105906176);                      // 1,048,576
  float* G = (float*)(w + 106954752);                        // 4,194,304
  unsigned short* statesb = (unsigned short*)(w + 111149056);// 16,777,216
  unsigned short* y = (unsigned short*)(w + 127926272);      // 33,554,432
  // aliases (lifetimes disjoint, single stream):
  unsigned short* xbf = (unsigned short*)(w + 111149056);    // = statesb region
  unsigned short* w_inT = (unsigned short*)(w + 33554432);   // = xbc region (8704x2048)
  unsigned short* w_outT = (unsigned short*)(w + 33554432);  // = xbc region (2048x4096)
  unsigned short* prefix = xbcraw;

  prep_kernel<<<dim3(8448), 256, 0, stream>>>(x, xbf, w_in, w_inT);
  gemm8_in<<<dim3(34, 16), 512, 0, stream>>>(xbf, w_inT, zbf, xbcraw, dtb);
  convdt_kernel<<<dim3(6144), 256, 0, stream>>>(xbcraw, conv_w, conv_b, xbc,
                                                dtb, dt_bias, A_log, Acs);
  g_kernel<<<dim3(16, 16), 256, 0, stream>>>(xbc, G);
  ssd_states<<<dim3(64, 8, 2), 512, 0, stream>>>(xbc, dtb, Acs, statesb);
  scan_states<<<dim3(64, 2), 256, 0, stream>>>(statesb, Acs, prefix);
  ssd_main<<<dim3(64, 8, 2), 512, 0, stream>>>(xbc, dtb, Acs, G, prefix, Dvec, y);
  transpose_conv<<<dim3(32, 64), 256, 0, stream>>>(w_out, w_outT, 4096, 2048);
  norm_kernel<<<dim3(4096), 256, 0, stream>>>(y, zbf, norm_w);
  gemm_p<<<dim3(16, 32), 256, 0, stream>>>(y, w_outT, 4096, out, x);
}

// Round 14
// 436.428 us; speedup vs baseline: 1.2028x; 1.0555x over previous
//
#include <hip/hip_runtime.h>
#include <math.h>

#define DEV __device__ __forceinline__

typedef __attribute__((ext_vector_type(4))) float f32x4;
typedef __attribute__((ext_vector_type(4))) unsigned short u16x4;
typedef __attribute__((ext_vector_type(8))) unsigned short u16x8;
typedef __attribute__((ext_vector_type(8))) __bf16 bfv8;

DEV unsigned short f2bf(float f) {
  unsigned u = __builtin_bit_cast(unsigned, f);
  u = (u + 0x7FFFu + ((u >> 16) & 1u)) >> 16;
  return (unsigned short)u;
}
DEV float bf2f(unsigned short h) {
  unsigned u = ((unsigned)h) << 16;
  return __builtin_bit_cast(float, u);
}

DEV f32x4 mfma16(u16x8 a, u16x8 b, f32x4 c) {
  return __builtin_amdgcn_mfma_f32_16x16x32_bf16(
      __builtin_bit_cast(bfv8, a), __builtin_bit_cast(bfv8, b), c, 0, 0, 0);
}

DEV void gload_lds16(const unsigned short* g, unsigned short* s) {
  __builtin_amdgcn_global_load_lds(
      (const __attribute__((address_space(1))) void*)g,
      (__attribute__((address_space(3))) void*)s, 16, 0, 0);
}

template <int N>
DEV void vmcnt_wait() {
  if constexpr (N == 0) asm volatile("s_waitcnt vmcnt(0)" ::: "memory");
  else if constexpr (N == 2) asm volatile("s_waitcnt vmcnt(2)" ::: "memory");
  else if constexpr (N == 4) asm volatile("s_waitcnt vmcnt(4)" ::: "memory");
}

// ---------------------------------------------------------------------------
// 8-phase 256x256 bf16 GEMM (R8 proven: 196 us, MfmaUtil 31.4), in_proj.
// K=2048, BK=64, 512 thr / 8 waves (4M x 2N), 2-deep LDS dbuf (128 KB).
// 4 phases/K-tile, 16 MFMA each; slot-staggered prefetch with counted
// vmcnt(4)/vmcnt(2) (never 0 in steady state). XOR chunk swizzle.
// ---------------------------------------------------------------------------
__global__ __launch_bounds__(512, 2) void gemm8_in(
    const unsigned short* __restrict__ A, const unsigned short* __restrict__ Bt,
    unsigned short* __restrict__ o_z, unsigned short* __restrict__ o_xbc,
    float* __restrict__ o_dt) {
  constexpr int K = 2048, NT = K / 64;
  __shared__ __align__(16) unsigned short As[2][256 * 64];
  __shared__ __align__(16) unsigned short Bs[2][256 * 64];
  const int tid = threadIdx.x;
  const int lane = tid & 63, w = tid >> 6;
  const int l16 = lane & 15, lq = lane >> 4;
  const int wr = w >> 1, wc = w & 1;
  const int nwg = gridDim.x * gridDim.y;
  int lin = blockIdx.y * gridDim.x + blockIdx.x;
  lin = (lin & 7) * (nwg >> 3) + (lin >> 3);
  const int m0 = (lin / gridDim.x) * 256, n0 = (lin % gridDim.x) * 256;
  const int srow = lane >> 3;
  const int schk = (lane & 7) ^ srow;
  const unsigned short* Ag = A + (size_t)(m0 + srow) * K + schk * 8;
  const unsigned short* Bg = Bt + (size_t)(n0 + srow) * K + schk * 8;
  const int px0 = lq ^ (l16 & 7);
  const int px1 = (4 + lq) ^ (l16 & 7);

  f32x4 acc[4][8] = {};

  auto stageA = [&](int p, int slot, int kt) {
    gload_lds16(Ag + (size_t)(slot * 64 + w * 8) * K + kt * 64,
                &As[p][(slot * 64 + w * 8) * 64]);
  };
  auto stageB = [&](int p, int slot, int kt) {
    gload_lds16(Bg + (size_t)(slot * 64 + w * 8) * K + kt * 64,
                &Bs[p][(slot * 64 + w * 8) * 64]);
  };
  auto rdA = [&](int p, int mf, int k2) -> u16x8 {
    const int row = wr * 64 + mf * 16 + l16;
    return *(const u16x8*)(&As[p][row * 64 + (k2 ? px1 : px0) * 8]);
  };
  auto rdB = [&](int p, int nf, int k2) -> u16x8 {
    const int row = wc * 128 + nf * 16 + l16;
    return *(const u16x8*)(&Bs[p][row * 64 + (k2 ? px1 : px0) * 8]);
  };

  stageA(0, 0, 0); stageA(0, 1, 0); stageA(0, 2, 0); stageA(0, 3, 0);
  stageB(0, 0, 0); stageB(0, 2, 0); stageB(0, 1, 0); stageB(0, 3, 0);
  vmcnt_wait<2>();
  __builtin_amdgcn_s_barrier();

  u16x8 a0[4], a1[4], b0[2], b1[2];
  for (int k = 0; k < NT; ++k) {
    const int p = k & 1, pn = p ^ 1;
    const bool st = (k + 1 < NT);
#pragma unroll
    for (int mf = 0; mf < 4; ++mf) { a0[mf] = rdA(p, mf, 0); a1[mf] = rdA(p, mf, 1); }
    b0[0] = rdB(p, 0, 0); b1[0] = rdB(p, 0, 1);
    b0[1] = rdB(p, 1, 0); b1[1] = rdB(p, 1, 1);
    if (st) { stageA(pn, 0, k + 1); stageA(pn, 1, k + 1); }
    __builtin_amdgcn_s_barrier();
    __builtin_amdgcn_s_setprio(1);
#pragma unroll
    for (int nf = 0; nf < 2; ++nf)
#pragma unroll
      for (int mf = 0; mf < 4; ++mf) {
        acc[mf][nf] = mfma16(a0[mf], b0[nf], acc[mf][nf]);
        acc[mf][nf] = mfma16(a1[mf], b1[nf], acc[mf][nf]);
      }
    __builtin_amdgcn_s_setprio(0);
    __builtin_amdgcn_s_barrier();
    b0[0] = rdB(p, 2, 0); b1[0] = rdB(p, 2, 1);
    b0[1] = rdB(p, 3, 0); b1[1] = rdB(p, 3, 1);
    if (st) { stageA(pn, 2, k + 1); stageA(pn, 3, k + 1); vmcnt_wait<4>(); }
    else vmcnt_wait<0>();
    __builtin_amdgcn_s_barrier();
    __builtin_amdgcn_s_setprio(1);
#pragma unroll
    for (int nf = 0; nf < 2; ++nf)
#pragma unroll
      for (int mf = 0; mf < 4; ++mf) {
        acc[mf][2 + nf] = mfma16(a0[mf], b0[nf], acc[mf][2 + nf]);
        acc[mf][2 + nf] = mfma16(a1[mf], b1[nf], acc[mf][2 + nf]);
      }
    __builtin_amdgcn_s_setprio(0);
    __builtin_amdgcn_s_barrier();
    b0[0] = rdB(p, 4, 0); b1[0] = rdB(p, 4, 1);
    b0[1] = rdB(p, 5, 0); b1[1] = rdB(p, 5, 1);
    if (st) { stageB(pn, 0, k + 1); stageB(pn, 2, k + 1); }
    __builtin_amdgcn_s_barrier();
    __builtin_amdgcn_s_setprio(1);
#pragma unroll
    for (int nf = 0; nf < 2; ++nf)
#pragma unroll
      for (int mf = 0; mf < 4; ++mf) {
        acc[mf][4 + nf] = mfma16(a0[mf], b0[nf], acc[mf][4 + nf]);
        acc[mf][4 + nf] = mfma16(a1[mf], b1[nf], acc[mf][4 + nf]);
      }
    __builtin_amdgcn_s_setprio(0);
    __builtin_amdgcn_s_barrier();
    b0[0] = rdB(p, 6, 0); b1[0] = rdB(p, 6, 1);
    b0[1] = rdB(p, 7, 0); b1[1] = rdB(p, 7, 1);
    if (st) { stageB(pn, 1, k + 1); stageB(pn, 3, k + 1); vmcnt_wait<2>(); }
    else vmcnt_wait<0>();
    __builtin_amdgcn_s_barrier();
    __builtin_amdgcn_s_setprio(1);
#pragma unroll
    for (int nf = 0; nf < 2; ++nf)
#pragma unroll
      for (int mf = 0; mf < 4; ++mf) {
        acc[mf][6 + nf] = mfma16(a0[mf], b0[nf], acc[mf][6 + nf]);
        acc[mf][6 + nf] = mfma16(a1[mf], b1[nf], acc[mf][6 + nf]);
      }
    __builtin_amdgcn_s_setprio(0);
    __builtin_amdgcn_s_barrier();
  }

#pragma unroll
  for (int mf = 0; mf < 4; ++mf) {
#pragma unroll
    for (int nf = 0; nf < 8; ++nf) {
      const int col = n0 + wc * 128 + nf * 16 + l16;
#pragma unroll
      for (int r = 0; r < 4; ++r) {
        const int row = m0 + wr * 64 + mf * 16 + lq * 4 + r;
        float v = acc[mf][nf][r];
        if (col < 4096) o_z[(size_t)row * 4096 + col] = f2bf(v);
        else if (col < 8448) o_xbc[(size_t)row * 4352 + (col - 4096)] = f2bf(v);
        else if (col < 8512) o_dt[(size_t)row * 64 + (col - 8448)] = v;
      }
    }
  }
}

// ---------------------------------------------------------------------------
// Pipelined bf16 GEMM (R7/R8 structure) for out_proj: 128x128, 4 waves,
// BK=32, 3-buffer ring, counted vmcnt(4). += resid -> f32 (N=2048).
// ---------------------------------------------------------------------------
__global__ __launch_bounds__(256, 3) void gemm_p(
    const unsigned short* __restrict__ A, const unsigned short* __restrict__ Bt,
    int K, float* __restrict__ o_c, const float* __restrict__ resid) {
  __shared__ __align__(16) unsigned short As[3][128 * 32];
  __shared__ __align__(16) unsigned short Bs[3][128 * 32];
  const int tid = threadIdx.x;
  const int lane = tid & 63, w = tid >> 6;
  const int l16 = lane & 15, lq = lane >> 4;
  const int wr = w >> 1, wc = w & 1;
  const int nwg = gridDim.x * gridDim.y;
  int lin = blockIdx.y * gridDim.x + blockIdx.x;
  lin = (lin & 7) * (nwg >> 3) + (lin >> 3);
  const int m0 = (lin / gridDim.x) * 128, n0 = (lin % gridDim.x) * 128;
  const int lrow = lane >> 2;
  const int gq = (lane & 3) ^ ((lrow >> 1) & 3);
  const int cq = lq ^ ((l16 >> 1) & 3);

  const unsigned short* Ag = A + (size_t)(m0 + lrow) * K + gq * 8;
  const unsigned short* Bg = Bt + (size_t)(n0 + lrow) * K + gq * 8;

  f32x4 acc[4][4] = {};

  auto stage = [&](int bi, int kt) {
#pragma unroll
    for (int i = 0; i < 2; ++i) {
      const int rb = (w + i * 4) * 16;
      gload_lds16(Ag + (size_t)rb * K + kt * 32, &As[bi][rb * 32]);
    }
#pragma unroll
    for (int i = 0; i < 2; ++i) {
      const int rb = (w + i * 4) * 16;
      gload_lds16(Bg + (size_t)rb * K + kt * 32, &Bs[bi][rb * 32]);
    }
  };

  const int nt = K / 32;
  stage(0, 0);
  stage(1, 1);

  for (int k = 0; k < nt; ++k) {
    const int cb = k % 3;
    if (k < nt - 1) vmcnt_wait<4>();
    else vmcnt_wait<0>();
    __builtin_amdgcn_s_barrier();
    if (k + 2 < nt) stage((k + 2) % 3, k + 2);

    u16x8 af[4], bf[4];
#pragma unroll
    for (int mf = 0; mf < 4; ++mf)
      af[mf] = *(const u16x8*)(&As[cb][(wr * 64 + mf * 16 + l16) * 32 + cq * 8]);
#pragma unroll
    for (int nf = 0; nf < 4; ++nf)
      bf[nf] = *(const u16x8*)(&Bs[cb][(wc * 64 + nf * 16 + l16) * 32 + cq * 8]);

    __builtin_amdgcn_s_setprio(1);
#pragma unroll
    for (int mf = 0; mf < 4; ++mf)
#pragma unroll
      for (int nf = 0; nf < 4; ++nf)
        acc[mf][nf] = mfma16(af[mf], bf[nf], acc[mf][nf]);
    __builtin_amdgcn_s_setprio(0);
  }

#pragma unroll
  for (int mf = 0; mf < 4; ++mf) {
#pragma unroll
    for (int nf = 0; nf < 4; ++nf) {
      const int col = n0 + wc * 64 + nf * 16 + l16;
#pragma unroll
      for (int r = 0; r < 4; ++r) {
        const int row = m0 + wr * 64 + mf * 16 + lq * 4 + r;
        size_t idx = (size_t)row * 2048 + col;
        o_c[idx] = acc[mf][nf][r] + resid[idx];
      }
    }
  }
}

// ---------------------------------------------------------------------------
// Prep: blocks 0..4095 convert x f32->bf16; blocks 4096..8447 transpose
// w_in [2048][8512] -> w_inT [8704][2048] bf16. Block-uniform branch.
// ---------------------------------------------------------------------------
__global__ __launch_bounds__(256) void prep_kernel(
    const float* __restrict__ x, unsigned short* __restrict__ xbf,
    const float* __restrict__ w_in, unsigned short* __restrict__ w_inT) {
  __shared__ __align__(16) unsigned short T[64][72];
  const int b = blockIdx.x;
  const int tid = threadIdx.x;
  if (b < 4096) {
    const size_t i = ((size_t)b * 256 + tid) * 8;
    f32x4 a = *(const f32x4*)(x + i);
    f32x4 c = *(const f32x4*)(x + i + 4);
    u16x8 o;
#pragma unroll
    for (int j = 0; j < 4; ++j) { o[j] = f2bf(a[j]); o[j + 4] = f2bf(c[j]); }
    *(u16x8*)(xbf + i) = o;
  } else {
    const int idx = b - 4096;
    const int c0 = (idx % 136) * 64, r0 = (idx / 136) * 64;
#pragma unroll
    for (int it = 0; it < 4; ++it) {
      int r = it * 16 + (tid >> 4);
      int c = (tid & 15) * 4;
      f32x4 v = {0.f, 0.f, 0.f, 0.f};
      if (c0 + c < 8512) v = *(const f32x4*)(w_in + (size_t)(r0 + r) * 8512 + c0 + c);
#pragma unroll
      for (int j = 0; j < 4; ++j) T[c + j][r] = f2bf(v[j]);
    }
    __syncthreads();
    const int nr = tid >> 2, kc = (tid & 3) * 16;
    u16x8 a = *(const u16x8*)(&T[nr][kc]);
    u16x8 c = *(const u16x8*)(&T[nr][kc + 8]);
    unsigned short* o = w_inT + (size_t)(c0 + nr) * 2048 + r0 + kc;
    *(u16x8*)o = a;
    *(u16x8*)(o + 8) = c;
  }
}

// ---------------------------------------------------------------------------
// Fused conv + dt. Blocks 0..5119: depthwise causal conv (L-tiled x4) +
// bias + SiLU. Blocks 5120..6143: dt softplus + per-chunk shuffle cumsum.
// ---------------------------------------------------------------------------
__global__ __launch_bounds__(256) void convdt_kernel(
    const unsigned short* __restrict__ raw, const float* __restrict__ cw,
    const float* __restrict__ cb, unsigned short* __restrict__ xbc,
    float* __restrict__ dtb, const float* __restrict__ dt_bias,
    const float* __restrict__ A_log, float* __restrict__ Acs) {
  __shared__ float wsum[4];
  const int b = blockIdx.x;
  const int tid = threadIdx.x;
  if (b < 5120) {
    const int ch4 = (b % 5) * 256 + tid;
    if (ch4 >= 1088) return;
    const int ch = ch4 * 4;
    const int r0 = (b / 5) * 4;
    const int l0 = r0 & 2047;
    f32x4 w0 = *(const f32x4*)(cw + ch * 4);
    f32x4 w1 = *(const f32x4*)(cw + ch * 4 + 4);
    f32x4 w2 = *(const f32x4*)(cw + ch * 4 + 8);
    f32x4 w3 = *(const f32x4*)(cw + ch * 4 + 12);
    f32x4 bias = *(const f32x4*)(cb + ch);
    f32x4 v[7];
#pragma unroll
    for (int i = 0; i < 7; ++i) {
      if (l0 - 3 + i >= 0) {
        u16x4 h = *(const u16x4*)(raw + (size_t)(r0 - 3 + i) * 4352 + ch);
        v[i] = (f32x4){bf2f(h[0]), bf2f(h[1]), bf2f(h[2]), bf2f(h[3])};
      } else {
        v[i] = (f32x4){0.f, 0.f, 0.f, 0.f};
      }
    }
#pragma unroll
    for (int j = 0; j < 4; ++j) {
      f32x4 acc = bias;
#pragma unroll
      for (int k = 0; k < 4; ++k) {
        acc[0] += w0[k] * v[j + k][0];
        acc[1] += w1[k] * v[j + k][1];
        acc[2] += w2[k] * v[j + k][2];
        acc[3] += w3[k] * v[j + k][3];
      }
      u16x4 o;
#pragma unroll
      for (int q = 0; q < 4; ++q) {
        float s = acc[q] / (1.0f + __expf(-acc[q]));
        o[q] = f2bf(s);
      }
      *(u16x4*)(xbc + (size_t)(r0 + j) * 4352 + ch) = o;
    }
  } else {
    const int blk = b - 5120;
    const int c = blk & 7, h = (blk >> 3) & 63, bb = blk >> 9;
    const int lane = tid & 63, w = tid >> 6;
    const int row = bb * 2048 + c * 256 + tid;
    float xv = dtb[(size_t)row * 64 + h] + dt_bias[h];
    float dt = (xv > 20.0f) ? xv : log1pf(__expf(xv));
    dtb[(size_t)row * 64 + h] = dt;
    float s = dt * (-__expf(A_log[h]));
#pragma unroll
    for (int off = 1; off < 64; off <<= 1) {
      float v = __shfl_up(s, off, 64);
      if (lane >= off) s += v;
    }
    if (lane == 63) wsum[w] = s;
    __syncthreads();
    float base = 0.0f;
#pragma unroll
    for (int i = 0; i < 4; ++i)
      if (i < w) base += wsum[i];
    Acs[((size_t)((bb * 64 + h) * 8 + c)) * 256 + tid] = s + base;
  }
}

// ---------------------------------------------------------------------------
// G[bc][i][j] = sum_n Cm[i][n]*Bm[j][n] (head-independent), bf16 output
// ---------------------------------------------------------------------------
__global__ __launch_bounds__(256) void g_kernel(
    const unsigned short* __restrict__ xbc, unsigned short* __restrict__ G) {
  const int bc = blockIdx.y;
  const int i0 = (blockIdx.x >> 2) * 64, j0 = (blockIdx.x & 3) * 64;
  const int tid = threadIdx.x;
  const int lane = tid & 63, w = tid >> 6;
  const int l16 = lane & 15, lq = lane >> 4;
  const unsigned short* base = xbc + (size_t)bc * 256 * 4352;
  f32x4 acc[4] = {};
#pragma unroll
  for (int ks = 0; ks < 4; ++ks) {
    int nb = ks * 32 + lq * 8;
    u16x8 af = *(const u16x8*)(base + (size_t)(i0 + w * 16 + l16) * 4352 + 4224 + nb);
#pragma unroll
    for (int jf = 0; jf < 4; ++jf) {
      u16x8 bb = *(const u16x8*)(base + (size_t)(j0 + jf * 16 + l16) * 4352 + 4096 + nb);
      acc[jf] = mfma16(af, bb, acc[jf]);
    }
  }
  unsigned short* Gt = G + (size_t)bc * 65536;
#pragma unroll
  for (int jf = 0; jf < 4; ++jf)
#pragma unroll
    for (int r = 0; r < 4; ++r)
      Gt[(i0 + w * 16 + lq * 4 + r) * 256 + j0 + jf * 16 + l16] =
          f2bf(acc[jf][r]);
}

// ---------------------------------------------------------------------------
// Per-chunk states: states[p][n] (bf16) = sum_t Bm[t][n]*decay(t)*X[t][p]
// ---------------------------------------------------------------------------
__global__ __launch_bounds__(512) void ssd_states(
    const unsigned short* __restrict__ xbc, const float* __restrict__ dtb,
    const float* __restrict__ Acs, unsigned short* __restrict__ statesb) {
  __shared__ __align__(16) unsigned short Xt[64 * 264];
  __shared__ __align__(16) unsigned short BmT[128 * 72];
  __shared__ float As_s[256];
  const int h = blockIdx.x, c = blockIdx.y, b = blockIdx.z;
  const int tid = threadIdx.x;
  const int lane = tid & 63, w = tid >> 6;
  const int l16 = lane & 15, lq = lane >> 4;
  const int row0 = b * 2048 + c * 256;

  if (tid < 256) As_s[tid] = Acs[((size_t)((b * 64 + h) * 8 + c)) * 256 + tid];
#pragma unroll
  for (int it = 0; it < 2; ++it) {
    int pb = tid & 15;
    int tb = it * 32 + (tid >> 4);
    float rr[4][4];
#pragma unroll
    for (int i = 0; i < 4; ++i) {
      int row = row0 + tb * 4 + i;
      u16x4 v = *(const u16x4*)(xbc + (size_t)row * 4352 + h * 64 + pb * 4);
      float dtv = dtb[(size_t)row * 64 + h];
#pragma unroll
      for (int j = 0; j < 4; ++j) rr[i][j] = bf2f(v[j]) * dtv;
    }
#pragma unroll
    for (int j = 0; j < 4; ++j) {
      u16x4 hh = {f2bf(rr[0][j]), f2bf(rr[1][j]), f2bf(rr[2][j]), f2bf(rr[3][j])};
      *(u16x4*)(&Xt[(pb * 4 + j) * 264 + tb * 4]) = hh;
    }
  }
  __syncthreads();

  f32x4 accS[4] = {};
  const float Alast = As_s[255];
  for (int part = 0; part < 4; ++part) {
    if (part) __syncthreads();
    {
      int nb = tid & 31;
      int tb = tid >> 5;
      float rr[4][4];
#pragma unroll
      for (int i = 0; i < 4; ++i) {
        int t = part * 64 + tb * 4 + i;
        int row = row0 + t;
        float dec = __expf(Alast - As_s[t]);
        u16x4 v = *(const u16x4*)(xbc + (size_t)row * 4352 + 4096 + nb * 4);
#pragma unroll
        for (int j = 0; j < 4; ++j) rr[i][j] = bf2f(v[j]) * dec;
      }
#pragma unroll
      for (int j = 0; j < 4; ++j) {
        u16x4 hh = {f2bf(rr[0][j]), f2bf(rr[1][j]), f2bf(rr[2][j]), f2bf(rr[3][j])};
        *(u16x4*)(&BmT[(nb * 4 + j) * 72 + tb * 4]) = hh;
      }
    }
    __syncthreads();
#pragma unroll
    for (int ks = 0; ks < 2; ++ks) {
      int toff = ks * 32 + lq * 8;
      u16x8 af = *(const u16x8*)(&BmT[(w * 16 + l16) * 72 + toff]);
#pragma unroll
      for (int pf = 0; pf < 4; ++pf) {
        u16x8 bfr = *(const u16x8*)(&Xt[(pf * 16 + l16) * 264 + part * 64 + toff]);
        accS[pf] = mfma16(af, bfr, accS[pf]);
      }
    }
  }
  unsigned short* Sp = statesb + (size_t)((b * 8 + c) * 64 + h) * 8192;
#pragma unroll
  for (int pf = 0; pf < 4; ++pf) {
    u16x4 hh = {f2bf(accS[pf][0]), f2bf(accS[pf][1]), f2bf(accS[pf][2]),
                f2bf(accS[pf][3])};
    *(u16x4*)(&Sp[(pf * 16 + l16) * 128 + w * 16 + lq * 4]) = hh;
  }
}

// ---------------------------------------------------------------------------
// Sequential chunk scan -> prefix states (bf16, [p][n]); grid (h, b, n-half)
// ---------------------------------------------------------------------------
__global__ __launch_bounds__(256) void scan_states(
    const unsigned short* __restrict__ statesb, const float* __restrict__ Acs,
    unsigned short* __restrict__ prefix) {
  const int h = blockIdx.x, b = blockIdx.y, nh = blockIdx.z;
  const int tid = threadIdx.x;
  const int p = tid >> 2, nq = nh * 64 + (tid & 3) * 16;
  float S[16];
#pragma unroll
  for (int i = 0; i < 16; ++i) S[i] = 0.0f;
  for (int cc = 0; cc < 8; ++cc) {
    size_t base = (size_t)((b * 8 + cc) * 64 + h) * 8192 + p * 128 + nq;
#pragma unroll
    for (int j = 0; j < 2; ++j) {
      u16x8 hh;
#pragma unroll
      for (int k = 0; k < 8; ++k) hh[k] = f2bf(S[j * 8 + k]);
      *(u16x8*)(prefix + base + j * 8) = hh;
    }
    float eAl = __expf(Acs[((size_t)((b * 64 + h) * 8 + cc)) * 256 + 255]);
#pragma unroll
    for (int j = 0; j < 2; ++j) {
      u16x8 v = *(const u16x8*)(statesb + base + j * 8);
#pragma unroll
      for (int k = 0; k < 8; ++k) S[j * 8 + k] = eAl * S[j * 8 + k] + bf2f(v[k]);
    }
  }
}

// ---------------------------------------------------------------------------
// Fused Y: Y_diag (G.*L @ X) + Y_off (exp(Acs)*Cm @ P^T) + D*xh -> y bf16
// G is bf16.
// ---------------------------------------------------------------------------
__global__ __launch_bounds__(512) void ssd_main(
    const unsigned short* __restrict__ xbc, const float* __restrict__ dtb,
    const float* __restrict__ Acs, const unsigned short* __restrict__ G,
    const unsigned short* __restrict__ prefix, const float* __restrict__ Dv,
    unsigned short* __restrict__ y) {
  __shared__ __align__(16) unsigned short Xt[64 * 264];
  __shared__ float As_s[256];
  const int h = blockIdx.x, c = blockIdx.y, b = blockIdx.z;
  const int tid = threadIdx.x;
  const int lane = tid & 63, w = tid >> 6;
  const int l16 = lane & 15, lq = lane >> 4;
  const int row0 = b * 2048 + c * 256;

  if (tid < 256) As_s[tid] = Acs[((size_t)((b * 64 + h) * 8 + c)) * 256 + tid];
#pragma unroll
  for (int it = 0; it < 2; ++it) {
    int pb = tid & 15;
    int tb = it * 32 + (tid >> 4);
    float rr[4][4];
#pragma unroll
    for (int i = 0; i < 4; ++i) {
      int row = row0 + tb * 4 + i;
      u16x4 v = *(const u16x4*)(xbc + (size_t)row * 4352 + h * 64 + pb * 4);
      float dtv = dtb[(size_t)row * 64 + h];
#pragma unroll
      for (int j = 0; j < 4; ++j) rr[i][j] = bf2f(v[j]) * dtv;
    }
#pragma unroll
    for (int j = 0; j < 4; ++j) {
      u16x4 hh = {f2bf(rr[0][j]), f2bf(rr[1][j]), f2bf(rr[2][j]), f2bf(rr[3][j])};
      *(u16x4*)(&Xt[(pb * 4 + j) * 264 + tb * 4]) = hh;
    }
  }
  __syncthreads();

  f32x4 acc[2][4] = {};
  const unsigned short* Gt = G + (size_t)(b * 8 + c) * 65536;
  for (int ks = 0; ks < 8; ++ks) {
    const int tb = ks * 32 + lq * 8;
    u16x8 bfr[4];
#pragma unroll
    for (int pf = 0; pf < 4; ++pf)
      bfr[pf] = *(const u16x8*)(&Xt[(pf * 16 + l16) * 264 + tb]);
#pragma unroll
    for (int mf = 0; mf < 2; ++mf) {
      const int i = w * 32 + mf * 16 + l16;
      const float ai = As_s[i];
      u16x8 gv = *(const u16x8*)(Gt + (size_t)i * 256 + tb);
      u16x8 af;
#pragma unroll
      for (int jj = 0; jj < 8; ++jj) {
        int j = tb + jj;
        float v = (i >= j) ? bf2f(gv[jj]) * __expf(ai - As_s[j]) : 0.0f;
        af[jj] = f2bf(v);
      }
#pragma unroll
      for (int pf = 0; pf < 4; ++pf)
        acc[mf][pf] = mfma16(af, bfr[pf], acc[mf][pf]);
    }
  }
  const unsigned short* Pf = prefix + (size_t)((b * 8 + c) * 64 + h) * 8192;
  for (int ks = 0; ks < 4; ++ks) {
    const int nb = ks * 32 + lq * 8;
    u16x8 bfr[4];
#pragma unroll
    for (int pf = 0; pf < 4; ++pf)
      bfr[pf] = *(const u16x8*)(Pf + (size_t)(pf * 16 + l16) * 128 + nb);
#pragma unroll
    for (int mf = 0; mf < 2; ++mf) {
      const int i = w * 32 + mf * 16 + l16;
      const float eAi = __expf(As_s[i]);
      u16x8 cv = *(const u16x8*)(xbc + (size_t)(row0 + i) * 4352 + 4224 + nb);
      u16x8 af;
#pragma unroll
      for (int jj = 0; jj < 8; ++jj) af[jj] = f2bf(bf2f(cv[jj]) * eAi);
#pragma unroll
      for (int pf = 0; pf < 4; ++pf)
        acc[mf][pf] = mfma16(af, bfr[pf], acc[mf][pf]);
    }
  }
  const float Dh = Dv[h];
#pragma unroll
  for (int mf = 0; mf < 2; ++mf) {
#pragma unroll
    for (int r = 0; r < 4; ++r) {
      int t = w * 32 + mf * 16 + lq * 4 + r;
      size_t row = (size_t)(row0 + t);
#pragma unroll
      for (int pf = 0; pf < 4; ++pf) {
        int p = pf * 16 + l16;
        float xh = bf2f(xbc[row * 4352 + h * 64 + p]);
        y[row * 4096 + h * 64 + p] = f2bf(acc[mf][pf][r] + Dh * xh);
      }
    }
  }
}

// ---------------------------------------------------------------------------
// Fused: blocks 0..4095 in-place rmsnorm(y*silu(z))*norm_w; blocks
// 4096..6143 transpose w_out [4096][2048] -> w_outT [2048][4096] bf16.
// ---------------------------------------------------------------------------
__global__ __launch_bounds__(256) void norm_trans(
    unsigned short* __restrict__ y, const unsigned short* __restrict__ zbf,
    const float* __restrict__ nw, const float* __restrict__ w_out,
    unsigned short* __restrict__ w_outT) {
  __shared__ __align__(16) unsigned short T[64][72];
  __shared__ float red[4];
  const int b = blockIdx.x;
  const int tid = threadIdx.x;
  if (b < 4096) {
    unsigned short* yr = y + (size_t)b * 4096;
    const unsigned short* zr = zbf + (size_t)b * 4096;
    float vals[16];
    float ss = 0.0f;
#pragma unroll
    for (int i = 0; i < 2; ++i) {
      int cb = i * 2048 + tid * 8;
      u16x8 yv = *(const u16x8*)(yr + cb);
      u16x8 zv = *(const u16x8*)(zr + cb);
#pragma unroll
      for (int j = 0; j < 8; ++j) {
        float z = bf2f(zv[j]);
        float g = bf2f(yv[j]) * (z / (1.0f + __expf(-z)));
        vals[i * 8 + j] = g;
        ss += g * g;
      }
    }
#pragma unroll
    for (int off = 32; off > 0; off >>= 1) ss += __shfl_xor(ss, off, 64);
    if ((tid & 63) == 0) red[tid >> 6] = ss;
    __syncthreads();
    float tot = red[0] + red[1] + red[2] + red[3];
    float rr = rsqrtf(tot * (1.0f / 4096.0f) + 1e-5f);
#pragma unroll
    for (int i = 0; i < 2; ++i) {
      int cb = i * 2048 + tid * 8;
      f32x4 w0 = *(const f32x4*)(nw + cb);
      f32x4 w1 = *(const f32x4*)(nw + cb + 4);
      u16x8 o;
#pragma unroll
      for (int j = 0; j < 8; ++j) {
        float wv = (j < 4) ? w0[j] : w1[j - 4];
        o[j] = f2bf(vals[i * 8 + j] * rr * wv);
      }
      *(u16x8*)(yr + cb) = o;
    }
  } else {
    const int idx = b - 4096;
    const int c0 = (idx & 31) * 64, r0 = (idx >> 5) * 64;
#pragma unroll
    for (int it = 0; it < 4; ++it) {
      int r = it * 16 + (tid >> 4);
      int c = (tid & 15) * 4;
      f32x4 v = *(const f32x4*)(w_out + (size_t)(r0 + r) * 2048 + c0 + c);
#pragma unroll
      for (int j = 0; j < 4; ++j) T[c + j][r] = f2bf(v[j]);
    }
    __syncthreads();
    const int nr = tid >> 2, kc = (tid & 3) * 16;
    u16x8 a = *(const u16x8*)(&T[nr][kc]);
    u16x8 c = *(const u16x8*)(&T[nr][kc + 8]);
    unsigned short* o = w_outT + (size_t)(c0 + nr) * 4096 + r0 + kc;
    *(u16x8*)o = a;
    *(u16x8*)(o + 8) = c;
  }
}

// ---------------------------------------------------------------------------
extern "C" void kernel_launch(void* const* d_in, const int* in_sizes, int n_in,
                              void* d_out, int out_size, void* d_ws,
                              size_t ws_size, hipStream_t stream) {
  const float* x = (const float*)d_in[0];
  const float* w_in = (const float*)d_in[1];
  const float* conv_w = (const float*)d_in[2];
  const float* conv_b = (const float*)d_in[3];
  const float* dt_bias = (const float*)d_in[4];
  const float* A_log = (const float*)d_in[5];
  const float* Dvec = (const float*)d_in[6];
  const float* norm_w = (const float*)d_in[7];
  const float* w_out = (const float*)d_in[8];
  float* out = (float*)d_out;

  char* w = (char*)d_ws;
  unsigned short* zbf = (unsigned short*)(w + 0);            // 33,554,432
  unsigned short* xbc = (unsigned short*)(w + 33554432);     // 35,651,584
  unsigned short* xbcraw = (unsigned short*)(w + 69206016);  // 35,651,584 (→prefix)
  float* dtb = (float*)(w + 104857600);                      // 1,048,576
  float* Acs = (float*)(w + 105906176);                      // 1,048,576
  unsigned short* G = (unsigned short*)(w + 106954752);      // 16*65536*2 = 2,097,152
  unsigned short* statesb = (unsigned short*)(w + 111149056);// 16,777,216
  unsigned short* y = (unsigned short*)(w + 127926272);      // 33,554,432
  // aliases (lifetimes disjoint, single stream):
  unsigned short* xbf = (unsigned short*)(w + 111149056);    // = statesb region
  unsigned short* w_inT = (unsigned short*)(w + 33554432);   // = xbc region (8704x2048)
  unsigned short* w_outT = (unsigned short*)(w + 33554432);  // = xbc region (2048x4096)
  unsigned short* prefix = xbcraw;

  prep_kernel<<<dim3(8448), 256, 0, stream>>>(x, xbf, w_in, w_inT);
  gemm8_in<<<dim3(34, 16), 512, 0, stream>>>(xbf, w_inT, zbf, xbcraw, dtb);
  convdt_kernel<<<dim3(6144), 256, 0, stream>>>(xbcraw, conv_w, conv_b, xbc,
                                                dtb, dt_bias, A_log, Acs);
  g_kernel<<<dim3(16, 16), 256, 0, stream>>>(xbc, G);
  ssd_states<<<dim3(64, 8, 2), 512, 0, stream>>>(xbc, dtb, Acs, statesb);
  scan_states<<<dim3(64, 2, 2), 256, 0, stream>>>(statesb, Acs, prefix);
  ssd_main<<<dim3(64, 8, 2), 512, 0, stream>>>(xbc, dtb, Acs, G, prefix, Dvec, y);
  norm_trans<<<dim3(6144), 256, 0, stream>>>(y, zbf, norm_w, w_out, w_outT);
  gemm_p<<<dim3(16, 32), 256, 0, stream>>>(y, w_outT, 4096, out, x);
}

// Round 15
// 430.969 us; speedup vs baseline: 1.2180x; 1.0127x over previous
//
#include <hip/hip_runtime.h>
#include <math.h>

#define DEV __device__ __forceinline__

typedef __attribute__((ext_vector_type(4))) float f32x4;
typedef __attribute__((ext_vector_type(4))) unsigned short u16x4;
typedef __attribute__((ext_vector_type(8))) unsigned short u16x8;
typedef __attribute__((ext_vector_type(8))) __bf16 bfv8;

DEV unsigned short f2bf(float f) {
  unsigned u = __builtin_bit_cast(unsigned, f);
  u = (u + 0x7FFFu + ((u >> 16) & 1u)) >> 16;
  return (unsigned short)u;
}
DEV float bf2f(unsigned short h) {
  unsigned u = ((unsigned)h) << 16;
  return __builtin_bit_cast(float, u);
}

DEV f32x4 mfma16(u16x8 a, u16x8 b, f32x4 c) {
  return __builtin_amdgcn_mfma_f32_16x16x32_bf16(
      __builtin_bit_cast(bfv8, a), __builtin_bit_cast(bfv8, b), c, 0, 0, 0);
}

DEV void gload_lds16(const unsigned short* g, unsigned short* s) {
  __builtin_amdgcn_global_load_lds(
      (const __attribute__((address_space(1))) void*)g,
      (__attribute__((address_space(3))) void*)s, 16, 0, 0);
}

template <int N>
DEV void vmcnt_wait() {
  if constexpr (N == 0) asm volatile("s_waitcnt vmcnt(0)" ::: "memory");
  else if constexpr (N == 2) asm volatile("s_waitcnt vmcnt(2)" ::: "memory");
  else if constexpr (N == 4) asm volatile("s_waitcnt vmcnt(4)" ::: "memory");
}

// ---------------------------------------------------------------------------
// 8-phase 256x256 bf16 GEMM (R8 proven: 196 us, MfmaUtil 31.8), in_proj.
// K=2048, BK=64, 512 thr / 8 waves (4M x 2N), 2-deep LDS dbuf (128 KB).
// 4 phases/K-tile, 16 MFMA each; slot-staggered prefetch with counted
// vmcnt(4)/vmcnt(2) (never 0 in steady state). XOR chunk swizzle.
// ---------------------------------------------------------------------------
__global__ __launch_bounds__(512, 2) void gemm8_in(
    const unsigned short* __restrict__ A, const unsigned short* __restrict__ Bt,
    unsigned short* __restrict__ o_z, unsigned short* __restrict__ o_xbc,
    float* __restrict__ o_dt) {
  constexpr int K = 2048, NT = K / 64;
  __shared__ __align__(16) unsigned short As[2][256 * 64];
  __shared__ __align__(16) unsigned short Bs[2][256 * 64];
  const int tid = threadIdx.x;
  const int lane = tid & 63, w = tid >> 6;
  const int l16 = lane & 15, lq = lane >> 4;
  const int wr = w >> 1, wc = w & 1;
  const int nwg = gridDim.x * gridDim.y;
  int lin = blockIdx.y * gridDim.x + blockIdx.x;
  lin = (lin & 7) * (nwg >> 3) + (lin >> 3);
  const int m0 = (lin / gridDim.x) * 256, n0 = (lin % gridDim.x) * 256;
  const int srow = lane >> 3;
  const int schk = (lane & 7) ^ srow;
  const unsigned short* Ag = A + (size_t)(m0 + srow) * K + schk * 8;
  const unsigned short* Bg = Bt + (size_t)(n0 + srow) * K + schk * 8;
  const int px0 = lq ^ (l16 & 7);
  const int px1 = (4 + lq) ^ (l16 & 7);

  f32x4 acc[4][8] = {};

  auto stageA = [&](int p, int slot, int kt) {
    gload_lds16(Ag + (size_t)(slot * 64 + w * 8) * K + kt * 64,
                &As[p][(slot * 64 + w * 8) * 64]);
  };
  auto stageB = [&](int p, int slot, int kt) {
    gload_lds16(Bg + (size_t)(slot * 64 + w * 8) * K + kt * 64,
                &Bs[p][(slot * 64 + w * 8) * 64]);
  };
  auto rdA = [&](int p, int mf, int k2) -> u16x8 {
    const int row = wr * 64 + mf * 16 + l16;
    return *(const u16x8*)(&As[p][row * 64 + (k2 ? px1 : px0) * 8]);
  };
  auto rdB = [&](int p, int nf, int k2) -> u16x8 {
    const int row = wc * 128 + nf * 16 + l16;
    return *(const u16x8*)(&Bs[p][row * 64 + (k2 ? px1 : px0) * 8]);
  };

  stageA(0, 0, 0); stageA(0, 1, 0); stageA(0, 2, 0); stageA(0, 3, 0);
  stageB(0, 0, 0); stageB(0, 2, 0); stageB(0, 1, 0); stageB(0, 3, 0);
  vmcnt_wait<2>();
  __builtin_amdgcn_s_barrier();

  u16x8 a0[4], a1[4], b0[2], b1[2];
  for (int k = 0; k < NT; ++k) {
    const int p = k & 1, pn = p ^ 1;
    const bool st = (k + 1 < NT);
#pragma unroll
    for (int mf = 0; mf < 4; ++mf) { a0[mf] = rdA(p, mf, 0); a1[mf] = rdA(p, mf, 1); }
    b0[0] = rdB(p, 0, 0); b1[0] = rdB(p, 0, 1);
    b0[1] = rdB(p, 1, 0); b1[1] = rdB(p, 1, 1);
    if (st) { stageA(pn, 0, k + 1); stageA(pn, 1, k + 1); }
    __builtin_amdgcn_s_barrier();
    __builtin_amdgcn_s_setprio(1);
#pragma unroll
    for (int nf = 0; nf < 2; ++nf)
#pragma unroll
      for (int mf = 0; mf < 4; ++mf) {
        acc[mf][nf] = mfma16(a0[mf], b0[nf], acc[mf][nf]);
        acc[mf][nf] = mfma16(a1[mf], b1[nf], acc[mf][nf]);
      }
    __builtin_amdgcn_s_setprio(0);
    __builtin_amdgcn_s_barrier();
    b0[0] = rdB(p, 2, 0); b1[0] = rdB(p, 2, 1);
    b0[1] = rdB(p, 3, 0); b1[1] = rdB(p, 3, 1);
    if (st) { stageA(pn, 2, k + 1); stageA(pn, 3, k + 1); vmcnt_wait<4>(); }
    else vmcnt_wait<0>();
    __builtin_amdgcn_s_barrier();
    __builtin_amdgcn_s_setprio(1);
#pragma unroll
    for (int nf = 0; nf < 2; ++nf)
#pragma unroll
      for (int mf = 0; mf < 4; ++mf) {
        acc[mf][2 + nf] = mfma16(a0[mf], b0[nf], acc[mf][2 + nf]);
        acc[mf][2 + nf] = mfma16(a1[mf], b1[nf], acc[mf][2 + nf]);
      }
    __builtin_amdgcn_s_setprio(0);
    __builtin_amdgcn_s_barrier();
    b0[0] = rdB(p, 4, 0); b1[0] = rdB(p, 4, 1);
    b0[1] = rdB(p, 5, 0); b1[1] = rdB(p, 5, 1);
    if (st) { stageB(pn, 0, k + 1); stageB(pn, 2, k + 1); }
    __builtin_amdgcn_s_barrier();
    __builtin_amdgcn_s_setprio(1);
#pragma unroll
    for (int nf = 0; nf < 2; ++nf)
#pragma unroll
      for (int mf = 0; mf < 4; ++mf) {
        acc[mf][4 + nf] = mfma16(a0[mf], b0[nf], acc[mf][4 + nf]);
        acc[mf][4 + nf] = mfma16(a1[mf], b1[nf], acc[mf][4 + nf]);
      }
    __builtin_amdgcn_s_setprio(0);
    __builtin_amdgcn_s_barrier();
    b0[0] = rdB(p, 6, 0); b1[0] = rdB(p, 6, 1);
    b0[1] = rdB(p, 7, 0); b1[1] = rdB(p, 7, 1);
    if (st) { stageB(pn, 1, k + 1); stageB(pn, 3, k + 1); vmcnt_wait<2>(); }
    else vmcnt_wait<0>();
    __builtin_amdgcn_s_barrier();
    __builtin_amdgcn_s_setprio(1);
#pragma unroll
    for (int nf = 0; nf < 2; ++nf)
#pragma unroll
      for (int mf = 0; mf < 4; ++mf) {
        acc[mf][6 + nf] = mfma16(a0[mf], b0[nf], acc[mf][6 + nf]);
        acc[mf][6 + nf] = mfma16(a1[mf], b1[nf], acc[mf][6 + nf]);
      }
    __builtin_amdgcn_s_setprio(0);
    __builtin_amdgcn_s_barrier();
  }

#pragma unroll
  for (int mf = 0; mf < 4; ++mf) {
#pragma unroll
    for (int nf = 0; nf < 8; ++nf) {
      const int col = n0 + wc * 128 + nf * 16 + l16;
#pragma unroll
      for (int r = 0; r < 4; ++r) {
        const int row = m0 + wr * 64 + mf * 16 + lq * 4 + r;
        float v = acc[mf][nf][r];
        if (col < 4096) o_z[(size_t)row * 4096 + col] = f2bf(v);
        else if (col < 8448) o_xbc[(size_t)row * 4352 + (col - 4096)] = f2bf(v);
        else if (col < 8512) o_dt[(size_t)row * 64 + (col - 8448)] = v;
      }
    }
  }
}

// ---------------------------------------------------------------------------
// Pipelined bf16 GEMM (R7/R8 structure) for out_proj: 128x128, 4 waves,
// BK=32, 3-buffer ring, counted vmcnt(4). += resid -> f32 (N=2048).
// ---------------------------------------------------------------------------
__global__ __launch_bounds__(256, 3) void gemm_p(
    const unsigned short* __restrict__ A, const unsigned short* __restrict__ Bt,
    int K, float* __restrict__ o_c, const float* __restrict__ resid) {
  __shared__ __align__(16) unsigned short As[3][128 * 32];
  __shared__ __align__(16) unsigned short Bs[3][128 * 32];
  const int tid = threadIdx.x;
  const int lane = tid & 63, w = tid >> 6;
  const int l16 = lane & 15, lq = lane >> 4;
  const int wr = w >> 1, wc = w & 1;
  const int nwg = gridDim.x * gridDim.y;
  int lin = blockIdx.y * gridDim.x + blockIdx.x;
  lin = (lin & 7) * (nwg >> 3) + (lin >> 3);
  const int m0 = (lin / gridDim.x) * 128, n0 = (lin % gridDim.x) * 128;
  const int lrow = lane >> 2;
  const int gq = (lane & 3) ^ ((lrow >> 1) & 3);
  const int cq = lq ^ ((l16 >> 1) & 3);

  const unsigned short* Ag = A + (size_t)(m0 + lrow) * K + gq * 8;
  const unsigned short* Bg = Bt + (size_t)(n0 + lrow) * K + gq * 8;

  f32x4 acc[4][4] = {};

  auto stage = [&](int bi, int kt) {
#pragma unroll
    for (int i = 0; i < 2; ++i) {
      const int rb = (w + i * 4) * 16;
      gload_lds16(Ag + (size_t)rb * K + kt * 32, &As[bi][rb * 32]);
    }
#pragma unroll
    for (int i = 0; i < 2; ++i) {
      const int rb = (w + i * 4) * 16;
      gload_lds16(Bg + (size_t)rb * K + kt * 32, &Bs[bi][rb * 32]);
    }
  };

  const int nt = K / 32;
  stage(0, 0);
  stage(1, 1);

  for (int k = 0; k < nt; ++k) {
    const int cb = k % 3;
    if (k < nt - 1) vmcnt_wait<4>();
    else vmcnt_wait<0>();
    __builtin_amdgcn_s_barrier();
    if (k + 2 < nt) stage((k + 2) % 3, k + 2);

    u16x8 af[4], bf[4];
#pragma unroll
    for (int mf = 0; mf < 4; ++mf)
      af[mf] = *(const u16x8*)(&As[cb][(wr * 64 + mf * 16 + l16) * 32 + cq * 8]);
#pragma unroll
    for (int nf = 0; nf < 4; ++nf)
      bf[nf] = *(const u16x8*)(&Bs[cb][(wc * 64 + nf * 16 + l16) * 32 + cq * 8]);

    __builtin_amdgcn_s_setprio(1);
#pragma unroll
    for (int mf = 0; mf < 4; ++mf)
#pragma unroll
      for (int nf = 0; nf < 4; ++nf)
        acc[mf][nf] = mfma16(af[mf], bf[nf], acc[mf][nf]);
    __builtin_amdgcn_s_setprio(0);
  }

#pragma unroll
  for (int mf = 0; mf < 4; ++mf) {
#pragma unroll
    for (int nf = 0; nf < 4; ++nf) {
      const int col = n0 + wc * 64 + nf * 16 + l16;
#pragma unroll
      for (int r = 0; r < 4; ++r) {
        const int row = m0 + wr * 64 + mf * 16 + lq * 4 + r;
        size_t idx = (size_t)row * 2048 + col;
        o_c[idx] = acc[mf][nf][r] + resid[idx];
      }
    }
  }
}

// ---------------------------------------------------------------------------
// Prep: blocks 0..4095 convert x f32->bf16; blocks 4096..8447 transpose
// w_in [2048][8512] -> w_inT [8704][2048] bf16. Block-uniform branch.
// ---------------------------------------------------------------------------
__global__ __launch_bounds__(256) void prep_kernel(
    const float* __restrict__ x, unsigned short* __restrict__ xbf,
    const float* __restrict__ w_in, unsigned short* __restrict__ w_inT) {
  __shared__ __align__(16) unsigned short T[64][72];
  const int b = blockIdx.x;
  const int tid = threadIdx.x;
  if (b < 4096) {
    const size_t i = ((size_t)b * 256 + tid) * 8;
    f32x4 a = *(const f32x4*)(x + i);
    f32x4 c = *(const f32x4*)(x + i + 4);
    u16x8 o;
#pragma unroll
    for (int j = 0; j < 4; ++j) { o[j] = f2bf(a[j]); o[j + 4] = f2bf(c[j]); }
    *(u16x8*)(xbf + i) = o;
  } else {
    const int idx = b - 4096;
    const int c0 = (idx % 136) * 64, r0 = (idx / 136) * 64;
#pragma unroll
    for (int it = 0; it < 4; ++it) {
      int r = it * 16 + (tid >> 4);
      int c = (tid & 15) * 4;
      f32x4 v = {0.f, 0.f, 0.f, 0.f};
      if (c0 + c < 8512) v = *(const f32x4*)(w_in + (size_t)(r0 + r) * 8512 + c0 + c);
#pragma unroll
      for (int j = 0; j < 4; ++j) T[c + j][r] = f2bf(v[j]);
    }
    __syncthreads();
    const int nr = tid >> 2, kc = (tid & 3) * 16;
    u16x8 a = *(const u16x8*)(&T[nr][kc]);
    u16x8 c = *(const u16x8*)(&T[nr][kc + 8]);
    unsigned short* o = w_inT + (size_t)(c0 + nr) * 2048 + r0 + kc;
    *(u16x8*)o = a;
    *(u16x8*)(o + 8) = c;
  }
}

// ---------------------------------------------------------------------------
// Fused conv + dt. Blocks 0..5119: depthwise causal conv (L-tiled x4) +
// bias + SiLU. Blocks 5120..6143: dt softplus + per-chunk shuffle cumsum.
// ---------------------------------------------------------------------------
__global__ __launch_bounds__(256) void convdt_kernel(
    const unsigned short* __restrict__ raw, const float* __restrict__ cw,
    const float* __restrict__ cb, unsigned short* __restrict__ xbc,
    float* __restrict__ dtb, const float* __restrict__ dt_bias,
    const float* __restrict__ A_log, float* __restrict__ Acs) {
  __shared__ float wsum[4];
  const int b = blockIdx.x;
  const int tid = threadIdx.x;
  if (b < 5120) {
    const int ch4 = (b % 5) * 256 + tid;
    if (ch4 >= 1088) return;
    const int ch = ch4 * 4;
    const int r0 = (b / 5) * 4;
    const int l0 = r0 & 2047;
    f32x4 w0 = *(const f32x4*)(cw + ch * 4);
    f32x4 w1 = *(const f32x4*)(cw + ch * 4 + 4);
    f32x4 w2 = *(const f32x4*)(cw + ch * 4 + 8);
    f32x4 w3 = *(const f32x4*)(cw + ch * 4 + 12);
    f32x4 bias = *(const f32x4*)(cb + ch);
    f32x4 v[7];
#pragma unroll
    for (int i = 0; i < 7; ++i) {
      if (l0 - 3 + i >= 0) {
        u16x4 h = *(const u16x4*)(raw + (size_t)(r0 - 3 + i) * 4352 + ch);
        v[i] = (f32x4){bf2f(h[0]), bf2f(h[1]), bf2f(h[2]), bf2f(h[3])};
      } else {
        v[i] = (f32x4){0.f, 0.f, 0.f, 0.f};
      }
    }
#pragma unroll
    for (int j = 0; j < 4; ++j) {
      f32x4 acc = bias;
#pragma unroll
      for (int k = 0; k < 4; ++k) {
        acc[0] += w0[k] * v[j + k][0];
        acc[1] += w1[k] * v[j + k][1];
        acc[2] += w2[k] * v[j + k][2];
        acc[3] += w3[k] * v[j + k][3];
      }
      u16x4 o;
#pragma unroll
      for (int q = 0; q < 4; ++q) {
        float s = acc[q] / (1.0f + __expf(-acc[q]));
        o[q] = f2bf(s);
      }
      *(u16x4*)(xbc + (size_t)(r0 + j) * 4352 + ch) = o;
    }
  } else {
    const int blk = b - 5120;
    const int c = blk & 7, h = (blk >> 3) & 63, bb = blk >> 9;
    const int lane = tid & 63, w = tid >> 6;
    const int row = bb * 2048 + c * 256 + tid;
    float xv = dtb[(size_t)row * 64 + h] + dt_bias[h];
    float dt = (xv > 20.0f) ? xv : log1pf(__expf(xv));
    dtb[(size_t)row * 64 + h] = dt;
    float s = dt * (-__expf(A_log[h]));
#pragma unroll
    for (int off = 1; off < 64; off <<= 1) {
      float v = __shfl_up(s, off, 64);
      if (lane >= off) s += v;
    }
    if (lane == 63) wsum[w] = s;
    __syncthreads();
    float base = 0.0f;
#pragma unroll
    for (int i = 0; i < 4; ++i)
      if (i < w) base += wsum[i];
    Acs[((size_t)((bb * 64 + h) * 8 + c)) * 256 + tid] = s + base;
  }
}

// ---------------------------------------------------------------------------
// Fused: blocks 0..1023 per-chunk states (states[p][n] bf16 = sum_t
// Bm[t][n]*decay(t)*X[t][p]); blocks 1024..1151 compute G (bf16, 2 old
// 64x64 tiles per block: waves 0-3 tile A, waves 4-7 tile B).
// ---------------------------------------------------------------------------
__global__ __launch_bounds__(512) void ssd_states_g(
    const unsigned short* __restrict__ xbc, const float* __restrict__ dtb,
    const float* __restrict__ Acs, unsigned short* __restrict__ statesb,
    unsigned short* __restrict__ G) {
  __shared__ __align__(16) unsigned short Xt[64 * 264];
  __shared__ __align__(16) unsigned short BmT[128 * 72];
  __shared__ float As_s[256];
  const int bx = blockIdx.x;
  const int tid = threadIdx.x;
  if (bx >= 1024) {
    // ---- G region
    const int t = (bx - 1024) * 2 + (tid >> 8);
    const int tl = tid & 255;
    const int lane = tl & 63, w = tl >> 6;
    const int l16 = lane & 15, lq = lane >> 4;
    const int bc = t >> 4;
    const int i0 = ((t >> 2) & 3) * 64, j0 = (t & 3) * 64;
    const unsigned short* base = xbc + (size_t)bc * 256 * 4352;
    f32x4 acc[4] = {};
#pragma unroll
    for (int ks = 0; ks < 4; ++ks) {
      int nb = ks * 32 + lq * 8;
      u16x8 af = *(const u16x8*)(base + (size_t)(i0 + w * 16 + l16) * 4352 + 4224 + nb);
#pragma unroll
      for (int jf = 0; jf < 4; ++jf) {
        u16x8 bb = *(const u16x8*)(base + (size_t)(j0 + jf * 16 + l16) * 4352 + 4096 + nb);
        acc[jf] = mfma16(af, bb, acc[jf]);
      }
    }
    unsigned short* Gt = G + (size_t)bc * 65536;
#pragma unroll
    for (int jf = 0; jf < 4; ++jf)
#pragma unroll
      for (int r = 0; r < 4; ++r)
        Gt[(i0 + w * 16 + lq * 4 + r) * 256 + j0 + jf * 16 + l16] =
            f2bf(acc[jf][r]);
    return;
  }
  // ---- states region
  const int h = bx & 63, c = (bx >> 6) & 7, b = bx >> 9;
  const int lane = tid & 63, w = tid >> 6;
  const int l16 = lane & 15, lq = lane >> 4;
  const int row0 = b * 2048 + c * 256;

  if (tid < 256) As_s[tid] = Acs[((size_t)((b * 64 + h) * 8 + c)) * 256 + tid];
#pragma unroll
  for (int it = 0; it < 2; ++it) {
    int pb = tid & 15;
    int tb = it * 32 + (tid >> 4);
    float rr[4][4];
#pragma unroll
    for (int i = 0; i < 4; ++i) {
      int row = row0 + tb * 4 + i;
      u16x4 v = *(const u16x4*)(xbc + (size_t)row * 4352 + h * 64 + pb * 4);
      float dtv = dtb[(size_t)row * 64 + h];
#pragma unroll
      for (int j = 0; j < 4; ++j) rr[i][j] = bf2f(v[j]) * dtv;
    }
#pragma unroll
    for (int j = 0; j < 4; ++j) {
      u16x4 hh = {f2bf(rr[0][j]), f2bf(rr[1][j]), f2bf(rr[2][j]), f2bf(rr[3][j])};
      *(u16x4*)(&Xt[(pb * 4 + j) * 264 + tb * 4]) = hh;
    }
  }
  __syncthreads();

  f32x4 accS[4] = {};
  const float Alast = As_s[255];
  for (int part = 0; part < 4; ++part) {
    if (part) __syncthreads();
    {
      int nb = tid & 31;
      int tb = tid >> 5;
      float rr[4][4];
#pragma unroll
      for (int i = 0; i < 4; ++i) {
        int t = part * 64 + tb * 4 + i;
        int row = row0 + t;
        float dec = __expf(Alast - As_s[t]);
        u16x4 v = *(const u16x4*)(xbc + (size_t)row * 4352 + 4096 + nb * 4);
#pragma unroll
        for (int j = 0; j < 4; ++j) rr[i][j] = bf2f(v[j]) * dec;
      }
#pragma unroll
      for (int j = 0; j < 4; ++j) {
        u16x4 hh = {f2bf(rr[0][j]), f2bf(rr[1][j]), f2bf(rr[2][j]), f2bf(rr[3][j])};
        *(u16x4*)(&BmT[(nb * 4 + j) * 72 + tb * 4]) = hh;
      }
    }
    __syncthreads();
#pragma unroll
    for (int ks = 0; ks < 2; ++ks) {
      int toff = ks * 32 + lq * 8;
      u16x8 af = *(const u16x8*)(&BmT[(w * 16 + l16) * 72 + toff]);
#pragma unroll
      for (int pf = 0; pf < 4; ++pf) {
        u16x8 bfr = *(const u16x8*)(&Xt[(pf * 16 + l16) * 264 + part * 64 + toff]);
        accS[pf] = mfma16(af, bfr, accS[pf]);
      }
    }
  }
  unsigned short* Sp = statesb + (size_t)((b * 8 + c) * 64 + h) * 8192;
#pragma unroll
  for (int pf = 0; pf < 4; ++pf) {
    u16x4 hh = {f2bf(accS[pf][0]), f2bf(accS[pf][1]), f2bf(accS[pf][2]),
                f2bf(accS[pf][3])};
    *(u16x4*)(&Sp[(pf * 16 + l16) * 128 + w * 16 + lq * 4]) = hh;
  }
}

// ---------------------------------------------------------------------------
// Sequential chunk scan -> prefix states (bf16, [p][n]); grid (h, b, n-half)
// ---------------------------------------------------------------------------
__global__ __launch_bounds__(256) void scan_states(
    const unsigned short* __restrict__ statesb, const float* __restrict__ Acs,
    unsigned short* __restrict__ prefix) {
  const int h = blockIdx.x, b = blockIdx.y, nh = blockIdx.z;
  const int tid = threadIdx.x;
  const int p = tid >> 2, nq = nh * 64 + (tid & 3) * 16;
  float S[16];
#pragma unroll
  for (int i = 0; i < 16; ++i) S[i] = 0.0f;
  for (int cc = 0; cc < 8; ++cc) {
    size_t base = (size_t)((b * 8 + cc) * 64 + h) * 8192 + p * 128 + nq;
#pragma unroll
    for (int j = 0; j < 2; ++j) {
      u16x8 hh;
#pragma unroll
      for (int k = 0; k < 8; ++k) hh[k] = f2bf(S[j * 8 + k]);
      *(u16x8*)(prefix + base + j * 8) = hh;
    }
    float eAl = __expf(Acs[((size_t)((b * 64 + h) * 8 + cc)) * 256 + 255]);
#pragma unroll
    for (int j = 0; j < 2; ++j) {
      u16x8 v = *(const u16x8*)(statesb + base + j * 8);
#pragma unroll
      for (int k = 0; k < 8; ++k) S[j * 8 + k] = eAl * S[j * 8 + k] + bf2f(v[k]);
    }
  }
}

// ---------------------------------------------------------------------------
// Fused Y: Y_diag (G.*L @ X) + Y_off (exp(Acs)*Cm @ P^T) + D*xh -> y bf16
// G is bf16.
// ---------------------------------------------------------------------------
__global__ __launch_bounds__(512) void ssd_main(
    const unsigned short* __restrict__ xbc, const float* __restrict__ dtb,
    const float* __restrict__ Acs, const unsigned short* __restrict__ G,
    const unsigned short* __restrict__ prefix, const float* __restrict__ Dv,
    unsigned short* __restrict__ y) {
  __shared__ __align__(16) unsigned short Xt[64 * 264];
  __shared__ float As_s[256];
  const int h = blockIdx.x, c = blockIdx.y, b = blockIdx.z;
  const int tid = threadIdx.x;
  const int lane = tid & 63, w = tid >> 6;
  const int l16 = lane & 15, lq = lane >> 4;
  const int row0 = b * 2048 + c * 256;

  if (tid < 256) As_s[tid] = Acs[((size_t)((b * 64 + h) * 8 + c)) * 256 + tid];
#pragma unroll
  for (int it = 0; it < 2; ++it) {
    int pb = tid & 15;
    int tb = it * 32 + (tid >> 4);
    float rr[4][4];
#pragma unroll
    for (int i = 0; i < 4; ++i) {
      int row = row0 + tb * 4 + i;
      u16x4 v = *(const u16x4*)(xbc + (size_t)row * 4352 + h * 64 + pb * 4);
      float dtv = dtb[(size_t)row * 64 + h];
#pragma unroll
      for (int j = 0; j < 4; ++j) rr[i][j] = bf2f(v[j]) * dtv;
    }
#pragma unroll
    for (int j = 0; j < 4; ++j) {
      u16x4 hh = {f2bf(rr[0][j]), f2bf(rr[1][j]), f2bf(rr[2][j]), f2bf(rr[3][j])};
      *(u16x4*)(&Xt[(pb * 4 + j) * 264 + tb * 4]) = hh;
    }
  }
  __syncthreads();

  f32x4 acc[2][4] = {};
  const unsigned short* Gt = G + (size_t)(b * 8 + c) * 65536;
  for (int ks = 0; ks < 8; ++ks) {
    const int tb = ks * 32 + lq * 8;
    u16x8 bfr[4];
#pragma unroll
    for (int pf = 0; pf < 4; ++pf)
      bfr[pf] = *(const u16x8*)(&Xt[(pf * 16 + l16) * 264 + tb]);
#pragma unroll
    for (int mf = 0; mf < 2; ++mf) {
      const int i = w * 32 + mf * 16 + l16;
      const float ai = As_s[i];
      u16x8 gv = *(const u16x8*)(Gt + (size_t)i * 256 + tb);
      u16x8 af;
#pragma unroll
      for (int jj = 0; jj < 8; ++jj) {
        int j = tb + jj;
        float v = (i >= j) ? bf2f(gv[jj]) * __expf(ai - As_s[j]) : 0.0f;
        af[jj] = f2bf(v);
      }
#pragma unroll
      for (int pf = 0; pf < 4; ++pf)
        acc[mf][pf] = mfma16(af, bfr[pf], acc[mf][pf]);
    }
  }
  const unsigned short* Pf = prefix + (size_t)((b * 8 + c) * 64 + h) * 8192;
  for (int ks = 0; ks < 4; ++ks) {
    const int nb = ks * 32 + lq * 8;
    u16x8 bfr[4];
#pragma unroll
    for (int pf = 0; pf < 4; ++pf)
      bfr[pf] = *(const u16x8*)(Pf + (size_t)(pf * 16 + l16) * 128 + nb);
#pragma unroll
    for (int mf = 0; mf < 2; ++mf) {
      const int i = w * 32 + mf * 16 + l16;
      const float eAi = __expf(As_s[i]);
      u16x8 cv = *(const u16x8*)(xbc + (size_t)(row0 + i) * 4352 + 4224 + nb);
      u16x8 af;
#pragma unroll
      for (int jj = 0; jj < 8; ++jj) af[jj] = f2bf(bf2f(cv[jj]) * eAi);
#pragma unroll
      for (int pf = 0; pf < 4; ++pf)
        acc[mf][pf] = mfma16(af, bfr[pf], acc[mf][pf]);
    }
  }
  const float Dh = Dv[h];
#pragma unroll
  for (int mf = 0; mf < 2; ++mf) {
#pragma unroll
    for (int r = 0; r < 4; ++r) {
      int t = w * 32 + mf * 16 + lq * 4 + r;
      size_t row = (size_t)(row0 + t);
#pragma unroll
      for (int pf = 0; pf < 4; ++pf) {
        int p = pf * 16 + l16;
        float xh = bf2f(xbc[row * 4352 + h * 64 + p]);
        y[row * 4096 + h * 64 + p] = f2bf(acc[mf][pf][r] + Dh * xh);
      }
    }
  }
}

// ---------------------------------------------------------------------------
// Fused: blocks 0..4095 in-place rmsnorm(y*silu(z))*norm_w; blocks
// 4096..6143 transpose w_out [4096][2048] -> w_outT [2048][4096] bf16.
// ---------------------------------------------------------------------------
__global__ __launch_bounds__(256) void norm_trans(
    unsigned short* __restrict__ y, const unsigned short* __restrict__ zbf,
    const float* __restrict__ nw, const float* __restrict__ w_out,
    unsigned short* __restrict__ w_outT) {
  __shared__ __align__(16) unsigned short T[64][72];
  __shared__ float red[4];
  const int b = blockIdx.x;
  const int tid = threadIdx.x;
  if (b < 4096) {
    unsigned short* yr = y + (size_t)b * 4096;
    const unsigned short* zr = zbf + (size_t)b * 4096;
    float vals[16];
    float ss = 0.0f;
#pragma unroll
    for (int i = 0; i < 2; ++i) {
      int cb = i * 2048 + tid * 8;
      u16x8 yv = *(const u16x8*)(yr + cb);
      u16x8 zv = *(const u16x8*)(zr + cb);
#pragma unroll
      for (int j = 0; j < 8; ++j) {
        float z = bf2f(zv[j]);
        float g = bf2f(yv[j]) * (z / (1.0f + __expf(-z)));
        vals[i * 8 + j] = g;
        ss += g * g;
      }
    }
#pragma unroll
    for (int off = 32; off > 0; off >>= 1) ss += __shfl_xor(ss, off, 64);
    if ((tid & 63) == 0) red[tid >> 6] = ss;
    __syncthreads();
    float tot = red[0] + red[1] + red[2] + red[3];
    float rr = rsqrtf(tot * (1.0f / 4096.0f) + 1e-5f);
#pragma unroll
    for (int i = 0; i < 2; ++i) {
      int cb = i * 2048 + tid * 8;
      f32x4 w0 = *(const f32x4*)(nw + cb);
      f32x4 w1 = *(const f32x4*)(nw + cb + 4);
      u16x8 o;
#pragma unroll
      for (int j = 0; j < 8; ++j) {
        float wv = (j < 4) ? w0[j] : w1[j - 4];
        o[j] = f2bf(vals[i * 8 + j] * rr * wv);
      }
      *(u16x8*)(yr + cb) = o;
    }
  } else {
    const int idx = b - 4096;
    const int c0 = (idx & 31) * 64, r0 = (idx >> 5) * 64;
#pragma unroll
    for (int it = 0; it < 4; ++it) {
      int r = it * 16 + (tid >> 4);
      int c = (tid & 15) * 4;
      f32x4 v = *(const f32x4*)(w_out + (size_t)(r0 + r) * 2048 + c0 + c);
#pragma unroll
      for (int j = 0; j < 4; ++j) T[c + j][r] = f2bf(v[j]);
    }
    __syncthreads();
    const int nr = tid >> 2, kc = (tid & 3) * 16;
    u16x8 a = *(const u16x8*)(&T[nr][kc]);
    u16x8 c = *(const u16x8*)(&T[nr][kc + 8]);
    unsigned short* o = w_outT + (size_t)(c0 + nr) * 4096 + r0 + kc;
    *(u16x8*)o = a;
    *(u16x8*)(o + 8) = c;
  }
}

// ---------------------------------------------------------------------------
extern "C" void kernel_launch(void* const* d_in, const int* in_sizes, int n_in,
                              void* d_out, int out_size, void* d_ws,
                              size_t ws_size, hipStream_t stream) {
  const float* x = (const float*)d_in[0];
  const float* w_in = (const float*)d_in[1];
  const float* conv_w = (const float*)d_in[2];
  const float* conv_b = (const float*)d_in[3];
  const float* dt_bias = (const float*)d_in[4];
  const float* A_log = (const float*)d_in[5];
  const float* Dvec = (const float*)d_in[6];
  const float* norm_w = (const float*)d_in[7];
  const float* w_out = (const float*)d_in[8];
  float* out = (float*)d_out;

  char* w = (char*)d_ws;
  unsigned short* zbf = (unsigned short*)(w + 0);            // 33,554,432
  unsigned short* xbc = (unsigned short*)(w + 33554432);     // 35,651,584
  unsigned short* xbcraw = (unsigned short*)(w + 69206016);  // 35,651,584 (→prefix)
  float* dtb = (float*)(w + 104857600);                      // 1,048,576
  float* Acs = (float*)(w + 105906176);                      // 1,048,576
  unsigned short* G = (unsigned short*)(w + 106954752);      // 2,097,152
  unsigned short* statesb = (unsigned short*)(w + 111149056);// 16,777,216
  unsigned short* y = (unsigned short*)(w + 127926272);      // 33,554,432
  // aliases (lifetimes disjoint, single stream):
  unsigned short* xbf = (unsigned short*)(w + 111149056);    // = statesb region
  unsigned short* w_inT = (unsigned short*)(w + 33554432);   // = xbc region (8704x2048)
  unsigned short* w_outT = (unsigned short*)(w + 33554432);  // = xbc region (2048x4096)
  unsigned short* prefix = xbcraw;

  prep_kernel<<<dim3(8448), 256, 0, stream>>>(x, xbf, w_in, w_inT);
  gemm8_in<<<dim3(34, 16), 512, 0, stream>>>(xbf, w_inT, zbf, xbcraw, dtb);
  convdt_kernel<<<dim3(6144), 256, 0, stream>>>(xbcraw, conv_w, conv_b, xbc,
                                                dtb, dt_bias, A_log, Acs);
  ssd_states_g<<<dim3(1152), 512, 0, stream>>>(xbc, dtb, Acs, statesb, G);
  scan_states<<<dim3(64, 2, 2), 256, 0, stream>>>(statesb, Acs, prefix);
  ssd_main<<<dim3(64, 8, 2), 512, 0, stream>>>(xbc, dtb, Acs, G, prefix, Dvec, y);
  norm_trans<<<dim3(6144), 256, 0, stream>>>(y, zbf, norm_w, w_out, w_outT);
  gemm_p<<<dim3(16, 32), 256, 0, stream>>>(y, w_outT, 4096, out, x);
}